// Round 1
// 552.969 us; speedup vs baseline: 1.0934x; 1.0934x over previous
//
#include <hip/hip_runtime.h>

typedef unsigned short u16;
using short4_t = __attribute__((ext_vector_type(4))) short;
using short8   = __attribute__((ext_vector_type(8))) short;
using floatx4  = __attribute__((ext_vector_type(4))) float;
using half_t   = _Float16;
using half2_t  = __attribute__((ext_vector_type(2))) _Float16;

constexpr int B_ = 256, T_ = 256, I_ = 16, H_ = 256, O_ = 11;
constexpr int HYP = 512;
constexpr int N1_ = H_ * I_ + H_ * H_ + 2 * H_;   // 70144
constexpr int N2_ = O_ * H_ + O_;                 // 2827
constexpr int GN  = N1_ + N2_;                    // 72971

// d_out is float32; offsets in float elements
constexpr size_t OUT_ACT  = 0;
constexpr size_t OUT_BLDI = (size_t)B_ * T_ * 3;            // 196608
constexpr size_t OUT_H    = OUT_BLDI + (size_t)B_ * T_ * 8; // 720896
constexpr size_t OUT_P1   = OUT_H + (size_t)B_ * H_;        // 786432
constexpr size_t OUT_P2   = OUT_P1 + (size_t)B_ * N1_;      // 18743296

// Raw workgroup barrier: LDS ordering only. Global stores stay IN FLIGHT
// (no vmcnt(0) drain, which __syncthreads would emit).
__device__ inline void bar_lds() {
    asm volatile("s_waitcnt lgkmcnt(0)\n\ts_barrier" ::: "memory");
}

__device__ inline float bf2f(u16 u) {
    union { unsigned int i; float f; } v; v.i = ((unsigned int)u) << 16; return v.f;
}
__device__ inline u16 f2bf(float f) {
    unsigned int x = __float_as_uint(f);
    unsigned int r = (x + 0x7fffu + ((x >> 16) & 1u)) >> 16;   // RNE, finite inputs
    return (u16)r;
}
__device__ inline float fdot2(half2_t a, half2_t b, float c) {
#if __has_builtin(__builtin_amdgcn_fdot2)
    return __builtin_amdgcn_fdot2(a, b, c, false);
#else
    return c + (float)a.x * (float)b.x + (float)a.y * (float)b.y;
#endif
}

// Per-tensor dtype sniff (wave-uniform).
__device__ inline bool sniff_f32(const void* p) {
    const u16* w = (const u16*)p;
    const int lane = threadIdx.x & 63;
    u16 u = w[lane * 2];
    unsigned e = (u >> 7) & 0xFF;
    bool inband = (u == 0) || (e >= 77 && e <= 140);
    return __popcll(__ballot(inband)) < 56;
}

__device__ inline float ldr(const void* p, size_t i, bool f32) {
    return f32 ? ((const float*)p)[i] : bf2f(((const u16*)p)[i]);
}

// ---------------- kernel 1: h1 = relu(bld @ W1 + b1) -> bf16 stash in out[0..131072) -------
__global__ void h1_kernel(const void* __restrict__ bld, const void* __restrict__ W1,
                          const void* __restrict__ b1, u16* __restrict__ h1) {
    const bool bldf = sniff_f32(bld);
    const bool w1f  = sniff_f32(W1);
    const bool b1f  = sniff_f32(b1);
    const int b = blockIdx.x;
    const int j = threadIdx.x;
    float acc = ldr(b1, j, b1f);
#pragma unroll
    for (int k = 0; k < 8; k++)
        acc += ldr(bld, b * 8 + k, bldf) * ldr(W1, k * HYP + j, w1f);
    h1[b * HYP + j] = f2bf(fmaxf(acc, 0.f));
}

// ---------------- kernel 2: flat = h1 @ W2 + b2 -> params1/params2 (f32, d_out) ------------
// LDS-staged B tile: per K-step (32 k), load 32x64 f32 coalesced, convert to bf16,
// ds_write_b64 into row-padded tile (68 u16 -> fragment ds_read_u16 are 2-way/free).
// Next tile register-prefetched; raw lgkm barriers keep those loads in flight.
constexpr int KS_ = 32;              // k per stage step
constexpr int NST = HYP / KS_;       // 16
constexpr int TP_ = 68;              // padded tile row in u16 (64 + 4)

template<bool W2F32>
__device__ void gemm_body(const u16* __restrict__ A, const void* __restrict__ Bm,
                          const void* __restrict__ b2, bool b2f,
                          float* __restrict__ out) {
    __shared__ alignas(16) u16 tile[KS_][TP_];

    const int nb   = blockIdx.x * 64;
    const int tid  = threadIdx.x;
    const int lane = tid & 63;
    const int wid  = tid >> 6;
    const int l15  = lane & 15;
    const int q    = lane >> 4;

    int  col[4]; bool cv[4];
#pragma unroll
    for (int j = 0; j < 4; j++) {
        int c = nb + j * 16 + l15;
        cv[j]  = (c < GN);
        col[j] = cv[j] ? c : (GN - 1);
    }

    const u16* ap[4];
#pragma unroll
    for (int i = 0; i < 4; i++)
        ap[i] = A + (wid * 64 + i * 16 + l15) * HYP + q * 8;

    // staging coords: thread covers row sk, 8 consecutive cols starting at sc
    const int sk = tid >> 3;          // 0..31
    const int sc = (tid & 7) * 8;     // 0,8,..,56
    const bool tail = (nb + 64 > GN); // block-uniform
    int scol[8];
#pragma unroll
    for (int e = 0; e < 8; e++) {
        int c = nb + sc + e;
        scol[e] = (tail && c >= GN) ? (GN - 1) : c;
    }

    float pf[8]; u16 pb[8];
    {   // prefetch ks=0
        const size_t ro = (size_t)sk * (size_t)GN;
#pragma unroll
        for (int e = 0; e < 8; e++) {
            if constexpr (W2F32) pf[e] = ((const float*)Bm)[ro + (size_t)scol[e]];
            else                 pb[e] = ((const u16*)Bm)[ro + (size_t)scol[e]];
        }
    }

    floatx4 acc[4][4] = {};

    for (int ks = 0; ks < NST; ks++) {
        // convert + stage current tile
        u16 w8[8];
#pragma unroll
        for (int e = 0; e < 8; e++) {
            if constexpr (W2F32) w8[e] = f2bf(pf[e]);
            else                 w8[e] = pb[e];
        }
        short4_t lo, hi;
        lo[0] = (short)w8[0]; lo[1] = (short)w8[1]; lo[2] = (short)w8[2]; lo[3] = (short)w8[3];
        hi[0] = (short)w8[4]; hi[1] = (short)w8[5]; hi[2] = (short)w8[6]; hi[3] = (short)w8[7];
        *(short4_t*)&tile[sk][sc]     = lo;   // 8B-aligned: sk*136 + sc*2
        *(short4_t*)&tile[sk][sc + 4] = hi;

        // prefetch next tile (consumed after next barrier -> hides under MFMA)
        if (ks + 1 < NST) {
            const size_t ro = (size_t)((ks + 1) * KS_ + sk) * (size_t)GN;
#pragma unroll
            for (int e = 0; e < 8; e++) {
                if constexpr (W2F32) pf[e] = ((const float*)Bm)[ro + (size_t)scol[e]];
                else                 pb[e] = ((const u16*)Bm)[ro + (size_t)scol[e]];
            }
        }
        bar_lds();   // stage writes visible; prefetch stays in flight

        short8 af[4];
#pragma unroll
        for (int i = 0; i < 4; i++)
            af[i] = *(const short8*)(ap[i] + ks * KS_);

        short8 bfr[4];
#pragma unroll
        for (int j = 0; j < 4; j++) {
#pragma unroll
            for (int t = 0; t < 8; t++)
                bfr[j][t] = (short)tile[q * 8 + t][j * 16 + l15];
        }
#pragma unroll
        for (int i = 0; i < 4; i++)
#pragma unroll
            for (int j = 0; j < 4; j++)
                acc[i][j] = __builtin_amdgcn_mfma_f32_16x16x32_bf16(af[i], bfr[j], acc[i][j], 0, 0, 0);
        bar_lds();   // all fragment reads done before next overwrite
    }

    const bool isP2 = (nb >= N1_);   // N1_ multiple of 64 -> no straddle
#pragma unroll
    for (int j = 0; j < 4; j++) {
        const float bias = ldr(b2, col[j], b2f);
#pragma unroll
        for (int i = 0; i < 4; i++) {
            const int mbase = wid * 64 + i * 16 + q * 4;
#pragma unroll
            for (int r = 0; r < 4; r++) {
                if (cv[j]) {
                    const float v = acc[i][j][r] + bias;
                    const int m = mbase + r;
                    size_t dst;
                    if (isP2) dst = OUT_P2 + (size_t)m * N2_ + (size_t)(col[j] - N1_);
                    else      dst = OUT_P1 + (size_t)m * N1_ + (size_t)col[j];
                    out[dst] = v;
                }
            }
        }
    }
}
__global__ __launch_bounds__(256) void gemm_kernel(const u16* A, const void* Bm,
                                                   const void* b2, float* out) {
    const bool w2f = sniff_f32(Bm);
    const bool b2f = sniff_f32(b2);
    if (w2f) gemm_body<true>(A, Bm, b2, b2f, out);
    else     gemm_body<false>(A, Bm, b2, b2f, out);
}

// ---------------- kernel 3: per-batch RNN scan --------------------------------------------
// 512 thr = 8 waves. Lane-pair decomposition: g = wave*32 + (lane>>1), hf = lane&1.
// The two half-row partials of g live in ADJACENT LANES of one wave -> reduce is a
// single shfl_xor(1): no pbuf, no reduce barrier. ONE raw lgkm-barrier per step;
// per-step global stores (projection) stay in flight across it.
__global__ __launch_bounds__(512) void rnn_kernel(const void* __restrict__ stim,
                                                  float* __restrict__ out) {
    const bool stf = sniff_f32(stim);
    const int b    = blockIdx.x;
    const int tid  = threadIdx.x;
    const int lane = tid & 63;
    const int wv   = tid >> 6;
    const int g    = wv * 32 + (lane >> 1);
    const int hf   = lane & 1;

    const float* p1 = out + OUT_P1 + (size_t)b * N1_;
    const float* p2 = out + OUT_P2 + (size_t)b * N2_;

    __shared__ alignas(16) half2_t hbuf[2][128];     // h as 256 halfs, double-buffered
    __shared__ alignas(16) half2_t stim_s[T_ * 8];   // stimulus[b] as half2

    // stage stimulus -> half2
    if (stf) {
        const float2* sp = (const float2*)stim + (size_t)b * T_ * 8;
        for (int idx = tid; idx < T_ * 8; idx += 512) {
            float2 v = sp[idx];
            half2_t h; h.x = (half_t)v.x; h.y = (half_t)v.y;
            stim_s[idx] = h;
        }
    } else {
        const unsigned int* sp = (const unsigned int*)((const u16*)stim + (size_t)b * T_ * I_);
        for (int idx = tid; idx < T_ * 8; idx += 512) {
            unsigned int u = sp[idx];
            union { unsigned int i; float f; } lo2, hi2;
            lo2.i = u << 16; hi2.i = u & 0xffff0000u;
            half2_t h; h.x = (half_t)lo2.f; h.y = (half_t)hi2.f;
            stim_s[idx] = h;
        }
    }

    // W_hh half-row -> registers: W_hh[g][hf*128 .. +127] as 64 half2
    half2_t Wr[64];
    {
        const float4* wp4 = (const float4*)(p1 + H_ * I_ + (size_t)g * H_ + hf * 128);
#pragma unroll
        for (int v = 0; v < 32; v++) {
            float4 r4 = wp4[v];
            half2_t h01, h23;
            h01.x = (half_t)r4.x; h01.y = (half_t)r4.y;
            h23.x = (half_t)r4.z; h23.y = (half_t)r4.w;
            Wr[v * 2 + 0] = h01;
            Wr[v * 2 + 1] = h23;
        }
    }

    // W_ih row + combined bias on even (hf==0) lanes
    half2_t Wih[8];
    float bc = 0.f;
    if (!hf) {
        const float4* ip = (const float4*)(p1 + (size_t)g * I_);
#pragma unroll
        for (int v = 0; v < 4; v++) {
            float4 r4 = ip[v];
            half2_t h01, h23;
            h01.x = (half_t)r4.x; h01.y = (half_t)r4.y;
            h23.x = (half_t)r4.z; h23.y = (half_t)r4.w;
            Wih[v * 2 + 0] = h01;
            Wih[v * 2 + 1] = h23;
        }
        bc = p1[H_ * I_ + H_ * H_ + g] + p1[H_ * I_ + H_ * H_ + H_ + g];
    }

    // W_out: 352 threads, o = tid>>5 (0..10), c = tid&31, 8 halfs each (balanced over 6 waves)
    half2_t Wo[4];
    float bo = 0.f;
    const int oo = tid >> 5, cc = tid & 31;
    const bool isproj = (tid < 352);
    if (isproj) {
        const float* wop = p2 + oo * H_ + cc * 8;    // p2 only 4B-aligned -> scalar
#pragma unroll
        for (int v = 0; v < 4; v++) {
            half2_t w;
            w.x = (half_t)wop[2 * v];
            w.y = (half_t)wop[2 * v + 1];
            Wo[v] = w;
        }
        bo = p2[O_ * H_ + oo];
    }

    if (tid < 128) {
        half2_t z; z.x = (half_t)0.f; z.y = (half_t)0.f;
        hbuf[0][tid] = z;
    }
    __syncthreads();   // one full sync after staging (one-time drain is fine)

    const size_t act_base  = OUT_ACT  + (size_t)b * T_ * 3;
    const size_t bldi_base = OUT_BLDI + (size_t)b * T_ * 8;

    auto do_proj = [&](const half2_t* hb, int tt) {
        if (isproj) {
            const half2_t* h2v = hb + cc * 4;
            float oa = 0.f;
#pragma unroll
            for (int v = 0; v < 4; v++) oa = fdot2(Wo[v], h2v[v], oa);
            oa += __shfl_xor(oa, 1);
            oa += __shfl_xor(oa, 2);
            oa += __shfl_xor(oa, 4);
            oa += __shfl_xor(oa, 8);
            oa += __shfl_xor(oa, 16);
            if (cc == 0) {
                float v2 = oa + bo;
                if (oo < 3) out[act_base  + (size_t)tt * 3 + oo]       = 1.f / (1.f + __expf(-v2));
                else        out[bldi_base + (size_t)tt * 8 + (oo - 3)] = v2;
            }
        }
    };

    for (int t = 0; t < T_; t++) {
        const int cur = t & 1;

        // projection of previous step's h (independent chain, hides under the dots)
        if (t > 0) do_proj(hbuf[cur], t - 1);

        // half-row matvec: W_hh[g][hf*128..] . h[hf*128..]
        const half2_t* hv = &hbuf[cur][hf * 64];
        float a0 = 0.f, a1 = 0.f, a2 = 0.f, a3 = 0.f;
#pragma unroll
        for (int jj = 0; jj < 64; jj += 4) {
            a0 = fdot2(Wr[jj + 0], hv[jj + 0], a0);
            a1 = fdot2(Wr[jj + 1], hv[jj + 1], a1);
            a2 = fdot2(Wr[jj + 2], hv[jj + 2], a2);
            a3 = fdot2(Wr[jj + 3], hv[jj + 3], a3);
        }
        float part = (a0 + a1) + (a2 + a3);
        if (!hf) {   // fused x_proj + biases on even lane
            float xa = bc;
            if (t > 0) {
                const half2_t* sv = &stim_s[(t - 1) * 8];
#pragma unroll
                for (int i2 = 0; i2 < 8; i2++) xa = fdot2(Wih[i2], sv[i2], xa);
            }
            part += xa;
        }
        part += __shfl_xor(part, 1);   // in-wave pair reduce: no LDS, no barrier
        if (!hf) {
            const float e  = __expf(2.f * part);
            const float hn = 1.f - 2.f / (e + 1.f);   // tanh(part)
            ((half_t*)hbuf[cur ^ 1])[g] = (half_t)hn;
            if (t == T_ - 1) out[OUT_H + (size_t)b * H_ + g] = hn;
        }
        bar_lds();   // ONE barrier/step; global stores remain in flight
    }
    do_proj(hbuf[0], T_ - 1);   // final timestep's projection
}

extern "C" void kernel_launch(void* const* d_in, const int* in_sizes, int n_in,
                              void* d_out, int out_size, void* d_ws, size_t ws_size,
                              hipStream_t stream) {
    (void)in_sizes; (void)n_in; (void)out_size; (void)d_ws; (void)ws_size;
    const void* bld  = d_in[0];
    const void* stim = d_in[1];
    const void* W1   = d_in[2];
    const void* b1   = d_in[3];
    const void* W2   = d_in[4];
    const void* b2   = d_in[5];
    float* out = (float*)d_out;
    u16* h1 = (u16*)out;   // 256x512 bf16 stash inside act region (rewritten by rnn)

    h1_kernel<<<B_, HYP, 0, stream>>>(bld, W1, b1, h1);
    gemm_kernel<<<(GN + 63) / 64, 256, 0, stream>>>(h1, W2, b2, out);
    rnn_kernel<<<B_, 512, 0, stream>>>(stim, out);
}

// Round 2
// 454.951 us; speedup vs baseline: 1.3290x; 1.2154x over previous
//
#include <hip/hip_runtime.h>

typedef unsigned short u16;
typedef unsigned int u32;
using short8   = __attribute__((ext_vector_type(8))) short;
using floatx4  = __attribute__((ext_vector_type(4))) float;
using half_t   = _Float16;
using half2_t  = __attribute__((ext_vector_type(2))) _Float16;
using halfx8   = __attribute__((ext_vector_type(8))) _Float16;

constexpr int B_ = 256, T_ = 256, I_ = 16, H_ = 256, O_ = 11;
constexpr int HYP = 512;
constexpr int N1_ = H_ * I_ + H_ * H_ + 2 * H_;   // 70144
constexpr int N2_ = O_ * H_ + O_;                 // 2827
constexpr int GN  = N1_ + N2_;                    // 72971

// d_out is float32; offsets in float elements
constexpr size_t OUT_ACT  = 0;
constexpr size_t OUT_BLDI = (size_t)B_ * T_ * 3;            // 196608
constexpr size_t OUT_H    = OUT_BLDI + (size_t)B_ * T_ * 8; // 720896
constexpr size_t OUT_P1   = OUT_H + (size_t)B_ * H_;        // 786432
constexpr size_t OUT_P2   = OUT_P1 + (size_t)B_ * N1_;      // 18743296

// Raw workgroup barrier: LDS ordering only (no vmcnt drain).
__device__ inline void bar_lds() {
    asm volatile("s_waitcnt lgkmcnt(0)\n\ts_barrier" ::: "memory");
}

__device__ inline float bf2f(u16 u) {
    union { u32 i; float f; } v; v.i = ((u32)u) << 16; return v.f;
}
__device__ inline u16 f2bf(float f) {
    u32 x = __float_as_uint(f);
    u32 r = (x + 0x7fffu + ((x >> 16) & 1u)) >> 16;   // RNE, finite inputs
    return (u16)r;
}
__device__ inline float fdot2(half2_t a, half2_t b, float c) {
#if __has_builtin(__builtin_amdgcn_fdot2)
    return __builtin_amdgcn_fdot2(a, b, c, false);
#else
    return c + (float)a.x * (float)b.x + (float)a.y * (float)b.y;
#endif
}

union H8 { halfx8 v; half2_t h2[4]; };

// Per-tensor dtype sniff (wave-uniform).
__device__ inline bool sniff_f32(const void* p) {
    const u16* w = (const u16*)p;
    const int lane = threadIdx.x & 63;
    u16 u = w[lane * 2];
    unsigned e = (u >> 7) & 0xFF;
    bool inband = (u == 0) || (e >= 77 && e <= 140);
    return __popcll(__ballot(inband)) < 56;
}

__device__ inline float ldr(const void* p, size_t i, bool f32) {
    return f32 ? ((const float*)p)[i] : bf2f(((const u16*)p)[i]);
}

// ---------------- kernel 1: h1 = relu(bld @ W1 + b1) -> bf16 stash in out[0..65536) --------
__global__ void h1_kernel(const void* __restrict__ bld, const void* __restrict__ W1,
                          const void* __restrict__ b1, u16* __restrict__ h1) {
    const bool bldf = sniff_f32(bld);
    const bool w1f  = sniff_f32(W1);
    const bool b1f  = sniff_f32(b1);
    const int b = blockIdx.x;
    const int j = threadIdx.x;
    float acc = ldr(b1, j, b1f);
#pragma unroll
    for (int k = 0; k < 8; k++)
        acc += ldr(bld, b * 8 + k, bldf) * ldr(W1, k * HYP + j, w1f);
    h1[b * HYP + j] = f2bf(fmaxf(acc, 0.f));
}

// ---------------- kernel 2: flat = h1 @ W2 + b2 -> params1/params2 (f32, d_out) ------------
// Transposed LDS tile tileT[col][k] (pad 40 halfs -> 80B rows, b128-aligned):
//   staging: thread (col = tid&63, kq = tid>>6) loads 8 k-rows of its col (coalesced across
//   lanes), converts, writes ONE ds_write_b128.
//   fragment: bfr[j] = one ds_read_b128 per j (was 32 ds_read_u16 per thread).
constexpr int KS_ = 32;              // k per stage step
constexpr int NST = HYP / KS_;       // 16
constexpr int TKP = 40;              // padded k-dim in u16 (32 + 8) -> 80B rows

template<bool W2F32>
__device__ void gemm_body(const u16* __restrict__ A, const void* __restrict__ Bm,
                          const void* __restrict__ b2, bool b2f,
                          float* __restrict__ out) {
    __shared__ alignas(16) u16 tileT[64][TKP];

    const int nb   = blockIdx.x * 64;
    const int tid  = threadIdx.x;
    const int lane = tid & 63;
    const int wid  = tid >> 6;
    const int l15  = lane & 15;
    const int q    = lane >> 4;

    int  col[4]; bool cv[4];
#pragma unroll
    for (int j = 0; j < 4; j++) {
        int c = nb + j * 16 + l15;
        cv[j]  = (c < GN);
        col[j] = cv[j] ? c : (GN - 1);
    }

    const u16* ap[4];
#pragma unroll
    for (int i = 0; i < 4; i++)
        ap[i] = A + (wid * 64 + i * 16 + l15) * HYP + q * 8;

    // staging coords: thread owns one col, 8 consecutive k's
    const int scol_i = tid & 63;
    const int kq     = tid >> 6;          // 0..3
    int gc = nb + scol_i;
    if (gc >= GN) gc = GN - 1;            // tail clamp (values masked at store)
    const size_t colOff = (size_t)gc;

    float pf[8]; u16 pb[8];
    {   // prefetch ks=0
#pragma unroll
        for (int e = 0; e < 8; e++) {
            const size_t ro = (size_t)(kq * 8 + e) * (size_t)GN + colOff;
            if constexpr (W2F32) pf[e] = ((const float*)Bm)[ro];
            else                 pb[e] = ((const u16*)Bm)[ro];
        }
    }

    floatx4 acc[4][4] = {};

    for (int ks = 0; ks < NST; ks++) {
        // convert + stage current k-chunk of this col (one b128 write)
        short8 wv8;
#pragma unroll
        for (int e = 0; e < 8; e++) {
            if constexpr (W2F32) wv8[e] = (short)f2bf(pf[e]);
            else                 wv8[e] = (short)pb[e];
        }
        *(short8*)&tileT[scol_i][kq * 8] = wv8;

        // prefetch next tile (stays in flight across raw barrier)
        if (ks + 1 < NST) {
#pragma unroll
            for (int e = 0; e < 8; e++) {
                const size_t ro = (size_t)((ks + 1) * KS_ + kq * 8 + e) * (size_t)GN + colOff;
                if constexpr (W2F32) pf[e] = ((const float*)Bm)[ro];
                else                 pb[e] = ((const u16*)Bm)[ro];
            }
        }
        bar_lds();   // stage writes visible; global prefetch stays in flight

        short8 af[4];
#pragma unroll
        for (int i = 0; i < 4; i++)
            af[i] = *(const short8*)(ap[i] + ks * KS_);

        short8 bfr[4];
#pragma unroll
        for (int j = 0; j < 4; j++)
            bfr[j] = *(const short8*)&tileT[j * 16 + l15][q * 8];

#pragma unroll
        for (int i = 0; i < 4; i++)
#pragma unroll
            for (int j = 0; j < 4; j++)
                acc[i][j] = __builtin_amdgcn_mfma_f32_16x16x32_bf16(af[i], bfr[j], acc[i][j], 0, 0, 0);
        bar_lds();   // all fragment reads done before next overwrite
    }

    const bool isP2 = (nb >= N1_);   // N1_ multiple of 64 -> no straddle
#pragma unroll
    for (int j = 0; j < 4; j++) {
        const float bias = ldr(b2, col[j], b2f);
#pragma unroll
        for (int i = 0; i < 4; i++) {
            const int mbase = wid * 64 + i * 16 + q * 4;
#pragma unroll
            for (int r = 0; r < 4; r++) {
                if (cv[j]) {
                    const float v = acc[i][j][r] + bias;
                    const int m = mbase + r;
                    size_t dst;
                    if (isP2) dst = OUT_P2 + (size_t)m * N2_ + (size_t)(col[j] - N1_);
                    else      dst = OUT_P1 + (size_t)m * N1_ + (size_t)col[j];
                    out[dst] = v;
                }
            }
        }
    }
}
__global__ __launch_bounds__(256) void gemm_kernel(const u16* A, const void* Bm,
                                                   const void* b2, float* out) {
    const bool w2f = sniff_f32(Bm);
    const bool b2f = sniff_f32(b2);
    if (w2f) gemm_body<true>(A, Bm, b2, b2f, out);
    else     gemm_body<false>(A, Bm, b2, b2f, out);
}

// ---------------- kernel 3: per-batch RNN scan --------------------------------------------
// 512 thr = 8 waves; g = wv*32 + (lane>>1), hf = lane&1 (pair reduce = 1 shfl_xor).
// h history lives in LDS rows of 264 halfs: [0..127] | 8-pad | [136..263]
//   -> even-lane chunks hit bank-group (t+c)%8, odd (t+c+1)%8: disjoint, conflict-free.
// Output projection done ONCE as a post-pass over the stored history (no per-step DS/stores).
constexpr int ROWH = 264;            // row stride in halfs (528 B)

__global__ __launch_bounds__(512) void rnn_kernel(const void* __restrict__ stim,
                                                  float* __restrict__ out) {
    const bool stf = sniff_f32(stim);
    const int b    = blockIdx.x;
    const int tid  = threadIdx.x;
    const int lane = tid & 63;
    const int wv   = tid >> 6;
    const int g    = wv * 32 + (lane >> 1);
    const int hf   = lane & 1;

    const float* p1 = out + OUT_P1 + (size_t)b * N1_;
    const float* p2 = out + OUT_P2 + (size_t)b * N2_;

    __shared__ alignas(16) half_t  hist[(T_ + 1) * ROWH];  // 135696 B
    __shared__ alignas(16) half2_t stim_s[T_ * 8];         // 8192 B
    __shared__ alignas(16) half_t  wo_s[O_ * ROWH];        // 5808 B

    // stage stimulus -> half2
    if (stf) {
        const float2* sp = (const float2*)stim + (size_t)b * T_ * 8;
        for (int idx = tid; idx < T_ * 8; idx += 512) {
            float2 v = sp[idx];
            half2_t h; h.x = (half_t)v.x; h.y = (half_t)v.y;
            stim_s[idx] = h;
        }
    } else {
        const u32* sp = (const u32*)((const u16*)stim + (size_t)b * T_ * I_);
        for (int idx = tid; idx < T_ * 8; idx += 512) {
            u32 u = sp[idx];
            union { u32 i; float f; } lo2, hi2;
            lo2.i = u << 16; hi2.i = u & 0xffff0000u;
            half2_t h; h.x = (half_t)lo2.f; h.y = (half_t)hi2.f;
            stim_s[idx] = h;
        }
    }

    // W_hh half-row -> registers: W_hh[g][hf*128 .. +127] as 64 half2
    half2_t Wr[64];
    {
        const float4* wp4 = (const float4*)(p1 + H_ * I_ + (size_t)g * H_ + hf * 128);
#pragma unroll
        for (int v = 0; v < 32; v++) {
            float4 r4 = wp4[v];
            half2_t h01, h23;
            h01.x = (half_t)r4.x; h01.y = (half_t)r4.y;
            h23.x = (half_t)r4.z; h23.y = (half_t)r4.w;
            Wr[v * 2 + 0] = h01;
            Wr[v * 2 + 1] = h23;
        }
    }

    // W_ih row + combined bias on even (hf==0) lanes
    half2_t Wih[8];
    float bc = 0.f;
    if (!hf) {
        const float4* ip = (const float4*)(p1 + (size_t)g * I_);
#pragma unroll
        for (int v = 0; v < 4; v++) {
            float4 r4 = ip[v];
            half2_t h01, h23;
            h01.x = (half_t)r4.x; h01.y = (half_t)r4.y;
            h23.x = (half_t)r4.z; h23.y = (half_t)r4.w;
            Wih[v * 2 + 0] = h01;
            Wih[v * 2 + 1] = h23;
        }
        bc = p1[H_ * I_ + H_ * H_ + g] + p1[H_ * I_ + H_ * H_ + H_ + g];
    }

    // h0 = 0 (row 0: 132 dwords)
    for (int idx = tid; idx < ROWH / 2; idx += 512)
        ((u32*)hist)[idx] = 0u;
    __syncthreads();

    const int goff = g + ((g >= 128) ? 8 : 0);   // write index within a row

    for (int t = 0; t < T_; t++) {
        const half_t* hrow = hist + (size_t)t * ROWH;
        const halfx8* hv8  = (const halfx8*)(hrow + hf * 136);

        float a0 = 0.f, a1 = 0.f, a2 = 0.f, a3 = 0.f;
#pragma unroll
        for (int c = 0; c < 16; c++) {
            H8 u; u.v = hv8[c];
            a0 = fdot2(Wr[c * 4 + 0], u.h2[0], a0);
            a1 = fdot2(Wr[c * 4 + 1], u.h2[1], a1);
            a2 = fdot2(Wr[c * 4 + 2], u.h2[2], a2);
            a3 = fdot2(Wr[c * 4 + 3], u.h2[3], a3);
        }
        float part = (a0 + a1) + (a2 + a3);

        if (!hf) {
            float xa = bc;
            if (t > 0) {   // x_proj: 2 wave-uniform b128 broadcast reads
                const halfx8* sp8 = (const halfx8*)(&stim_s[(t - 1) * 8]);
                H8 u0, u1; u0.v = sp8[0]; u1.v = sp8[1];
                xa = fdot2(Wih[0], u0.h2[0], xa);
                xa = fdot2(Wih[1], u0.h2[1], xa);
                xa = fdot2(Wih[2], u0.h2[2], xa);
                xa = fdot2(Wih[3], u0.h2[3], xa);
                xa = fdot2(Wih[4], u1.h2[0], xa);
                xa = fdot2(Wih[5], u1.h2[1], xa);
                xa = fdot2(Wih[6], u1.h2[2], xa);
                xa = fdot2(Wih[7], u1.h2[3], xa);
            }
            part += xa;
        }
        part += __shfl_xor(part, 1);   // pair reduce, in-wave

        if (!hf) {
            const float e  = __expf(2.f * part);
            const float hn = 1.f - 2.f / (e + 1.f);   // tanh
            hist[(size_t)(t + 1) * ROWH + goff] = (half_t)hn;
            if (t == T_ - 1) out[OUT_H + (size_t)b * H_ + g] = hn;
        }
        bar_lds();   // ONE barrier/step, LDS-only drain
    }

    // ---------------- post-pass: output projection over stored history -------------------
    __syncthreads();
    for (int idx = tid; idx < O_ * H_; idx += 512) {
        const int o = idx >> 8, c = idx & 255;
        wo_s[o * ROWH + c + ((c >= 128) ? 8 : 0)] = (half_t)p2[idx];
    }
    __syncthreads();

    {
        const int t   = tid & 255;
        const int par = tid >> 8;                  // o-parity
        const half_t* hr_ = hist + (size_t)(t + 1) * ROWH;

        halfx8 hv[32];
        {
            const halfx8* h8a = (const halfx8*)hr_;
            const halfx8* h8b = (const halfx8*)(hr_ + 136);
#pragma unroll
            for (int c = 0; c < 16; c++) hv[c] = h8a[c];
#pragma unroll
            for (int c = 0; c < 16; c++) hv[16 + c] = h8b[c];
        }

        const size_t act_base  = OUT_ACT  + (size_t)b * T_ * 3 + (size_t)t * 3;
        const size_t bldi_base = OUT_BLDI + (size_t)b * T_ * 8 + (size_t)t * 8;

        for (int o = par; o < O_; o += 2) {
            const halfx8* w8a = (const halfx8*)(wo_s + o * ROWH);
            const halfx8* w8b = (const halfx8*)(wo_s + o * ROWH + 136);
            float d0 = 0.f, d1 = 0.f, d2 = 0.f, d3 = 0.f;
#pragma unroll
            for (int c = 0; c < 16; c++) {
                H8 hu, wu; hu.v = hv[c]; wu.v = w8a[c];
                d0 = fdot2(wu.h2[0], hu.h2[0], d0);
                d1 = fdot2(wu.h2[1], hu.h2[1], d1);
                d2 = fdot2(wu.h2[2], hu.h2[2], d2);
                d3 = fdot2(wu.h2[3], hu.h2[3], d3);
            }
#pragma unroll
            for (int c = 0; c < 16; c++) {
                H8 hu, wu; hu.v = hv[16 + c]; wu.v = w8b[c];
                d0 = fdot2(wu.h2[0], hu.h2[0], d0);
                d1 = fdot2(wu.h2[1], hu.h2[1], d1);
                d2 = fdot2(wu.h2[2], hu.h2[2], d2);
                d3 = fdot2(wu.h2[3], hu.h2[3], d3);
            }
            float v2 = (d0 + d1) + (d2 + d3) + p2[O_ * H_ + o];
            if (o < 3) out[act_base + o] = 1.f / (1.f + __expf(-v2));
            else       out[bldi_base + (o - 3)] = v2;
        }
    }
}

extern "C" void kernel_launch(void* const* d_in, const int* in_sizes, int n_in,
                              void* d_out, int out_size, void* d_ws, size_t ws_size,
                              hipStream_t stream) {
    (void)in_sizes; (void)n_in; (void)out_size; (void)d_ws; (void)ws_size;
    const void* bld  = d_in[0];
    const void* stim = d_in[1];
    const void* W1   = d_in[2];
    const void* b1   = d_in[3];
    const void* W2   = d_in[4];
    const void* b2   = d_in[5];
    float* out = (float*)d_out;
    u16* h1 = (u16*)out;   // 256x512 bf16 stash inside act region (rewritten by rnn post-pass)

    h1_kernel<<<B_, HYP, 0, stream>>>(bld, W1, b1, h1);
    gemm_kernel<<<(GN + 63) / 64, 256, 0, stream>>>(h1, W2, b2, out);
    rnn_kernel<<<B_, 512, 0, stream>>>(stim, out);
}

// Round 4
// 452.815 us; speedup vs baseline: 1.3352x; 1.0047x over previous
//
#include <hip/hip_runtime.h>

typedef unsigned short u16;
typedef unsigned int u32;
using short8   = __attribute__((ext_vector_type(8))) short;
using floatx4  = __attribute__((ext_vector_type(4))) float;
using half_t   = _Float16;
using half2_t  = __attribute__((ext_vector_type(2))) _Float16;
using halfx8   = __attribute__((ext_vector_type(8))) _Float16;

constexpr int B_ = 256, T_ = 256, I_ = 16, H_ = 256, O_ = 11;
constexpr int HYP = 512;
constexpr int N1_ = H_ * I_ + H_ * H_ + 2 * H_;   // 70144
constexpr int N2_ = O_ * H_ + O_;                 // 2827
constexpr int GN  = N1_ + N2_;                    // 72971

// d_out is float32; offsets in float elements
constexpr size_t OUT_ACT  = 0;
constexpr size_t OUT_BLDI = (size_t)B_ * T_ * 3;            // 196608
constexpr size_t OUT_H    = OUT_BLDI + (size_t)B_ * T_ * 8; // 720896
constexpr size_t OUT_P1   = OUT_H + (size_t)B_ * H_;        // 786432
constexpr size_t OUT_P2   = OUT_P1 + (size_t)B_ * N1_;      // 18743296

// Raw workgroup barrier: LDS ordering only (no vmcnt drain).
__device__ inline void bar_lds() {
    asm volatile("s_waitcnt lgkmcnt(0)\n\ts_barrier" ::: "memory");
}

__device__ inline float bf2f(u16 u) {
    union { u32 i; float f; } v; v.i = ((u32)u) << 16; return v.f;
}
__device__ inline u16 f2bf(float f) {
    u32 x = __float_as_uint(f);
    u32 r = (x + 0x7fffu + ((x >> 16) & 1u)) >> 16;   // RNE, finite inputs
    return (u16)r;
}

// Per-tensor dtype sniff (wave-uniform).
__device__ inline bool sniff_f32(const void* p) {
    const u16* w = (const u16*)p;
    const int lane = threadIdx.x & 63;
    u16 u = w[lane * 2];
    unsigned e = (u >> 7) & 0xFF;
    bool inband = (u == 0) || (e >= 77 && e <= 140);
    return __popcll(__ballot(inband)) < 56;
}

__device__ inline float ldr(const void* p, size_t i, bool f32) {
    return f32 ? ((const float*)p)[i] : bf2f(((const u16*)p)[i]);
}

// ---------------- kernel 1: h1 = relu(bld @ W1 + b1) -> bf16 stash in out[0..65536) --------
__global__ void h1_kernel(const void* __restrict__ bld, const void* __restrict__ W1,
                          const void* __restrict__ b1, u16* __restrict__ h1) {
    const bool bldf = sniff_f32(bld);
    const bool w1f  = sniff_f32(W1);
    const bool b1f  = sniff_f32(b1);
    const int b = blockIdx.x;
    const int j = threadIdx.x;
    float acc = ldr(b1, j, b1f);
#pragma unroll
    for (int k = 0; k < 8; k++)
        acc += ldr(bld, b * 8 + k, bldf) * ldr(W1, k * HYP + j, w1f);
    h1[b * HYP + j] = f2bf(fmaxf(acc, 0.f));
}

// ---------------- kernel 2: flat = h1 @ W2 + b2 -> params1/params2 (f32, d_out) ------------
constexpr int KS_ = 32;              // k per stage step
constexpr int NST = HYP / KS_;       // 16
constexpr int TKP = 40;              // padded k-dim in u16 (32 + 8) -> 80B rows

template<bool W2F32>
__device__ void gemm_body(const u16* __restrict__ A, const void* __restrict__ Bm,
                          const void* __restrict__ b2, bool b2f,
                          float* __restrict__ out) {
    __shared__ alignas(16) u16 tileT[64][TKP];

    const int nb   = blockIdx.x * 64;
    const int tid  = threadIdx.x;
    const int lane = tid & 63;
    const int wid  = tid >> 6;
    const int l15  = lane & 15;
    const int q    = lane >> 4;

    int  col[4]; bool cv[4];
#pragma unroll
    for (int j = 0; j < 4; j++) {
        int c = nb + j * 16 + l15;
        cv[j]  = (c < GN);
        col[j] = cv[j] ? c : (GN - 1);
    }

    const u16* ap[4];
#pragma unroll
    for (int i = 0; i < 4; i++)
        ap[i] = A + (wid * 64 + i * 16 + l15) * HYP + q * 8;

    const int scol_i = tid & 63;
    const int kq     = tid >> 6;          // 0..3
    int gc = nb + scol_i;
    if (gc >= GN) gc = GN - 1;            // tail clamp (values masked at store)
    const size_t colOff = (size_t)gc;

    float pf[8]; u16 pb[8];
    {   // prefetch ks=0
#pragma unroll
        for (int e = 0; e < 8; e++) {
            const size_t ro = (size_t)(kq * 8 + e) * (size_t)GN + colOff;
            if constexpr (W2F32) pf[e] = ((const float*)Bm)[ro];
            else                 pb[e] = ((const u16*)Bm)[ro];
        }
    }

    floatx4 acc[4][4] = {};

    for (int ks = 0; ks < NST; ks++) {
        short8 wv8;
#pragma unroll
        for (int e = 0; e < 8; e++) {
            if constexpr (W2F32) wv8[e] = (short)f2bf(pf[e]);
            else                 wv8[e] = (short)pb[e];
        }
        *(short8*)&tileT[scol_i][kq * 8] = wv8;

        if (ks + 1 < NST) {
#pragma unroll
            for (int e = 0; e < 8; e++) {
                const size_t ro = (size_t)((ks + 1) * KS_ + kq * 8 + e) * (size_t)GN + colOff;
                if constexpr (W2F32) pf[e] = ((const float*)Bm)[ro];
                else                 pb[e] = ((const u16*)Bm)[ro];
            }
        }
        bar_lds();   // stage writes visible; global prefetch stays in flight

        short8 af[4];
#pragma unroll
        for (int i = 0; i < 4; i++)
            af[i] = *(const short8*)(ap[i] + ks * KS_);

        short8 bfr[4];
#pragma unroll
        for (int j = 0; j < 4; j++)
            bfr[j] = *(const short8*)&tileT[j * 16 + l15][q * 8];

#pragma unroll
        for (int i = 0; i < 4; i++)
#pragma unroll
            for (int j = 0; j < 4; j++)
                acc[i][j] = __builtin_amdgcn_mfma_f32_16x16x32_bf16(af[i], bfr[j], acc[i][j], 0, 0, 0);
        bar_lds();
    }

    const bool isP2 = (nb >= N1_);   // N1_ multiple of 64 -> no straddle
#pragma unroll
    for (int j = 0; j < 4; j++) {
        const float bias = ldr(b2, col[j], b2f);
#pragma unroll
        for (int i = 0; i < 4; i++) {
            const int mbase = wid * 64 + i * 16 + q * 4;
#pragma unroll
            for (int r = 0; r < 4; r++) {
                if (cv[j]) {
                    const float v = acc[i][j][r] + bias;
                    const int m = mbase + r;
                    size_t dst;
                    if (isP2) dst = OUT_P2 + (size_t)m * N2_ + (size_t)(col[j] - N1_);
                    else      dst = OUT_P1 + (size_t)m * N1_ + (size_t)col[j];
                    out[dst] = v;
                }
            }
        }
    }
}
__global__ __launch_bounds__(256) void gemm_kernel(const u16* A, const void* Bm,
                                                   const void* b2, float* out) {
    const bool w2f = sniff_f32(Bm);
    const bool b2f = sniff_f32(b2);
    if (w2f) gemm_body<true>(A, Bm, b2, b2f, out);
    else     gemm_body<false>(A, Bm, b2, b2f, out);
}

// ---------------- kernel 3: per-batch RNN scan via MFMA -----------------------------------
// 256 thr = 4 waves, 1 block/batch/CU. Wave w owns output tiles 4w..4w+3 (64 g's).
// W_hh + [W_ih | bias] live in registers as B-fragments (halfx8 Wf[4][9]).
// A-operand (h) read with lane-addr depending only on lane>>4 => every A-row holds the
// same h vector: matvec result replicated in all 16 D-rows, k-reduction inside MFMA,
// no shuffles/LDS reduce. Bias folds in via x_ext slot16 = 1.0, B slot16 = b_ih+b_hh.
// Per step: 9 broadcast ds_read_b128 + 36 MFMA + tanh + 2B ds_write + ONE raw barrier.
// Output projection = MFMA post-pass over LDS h-history.
constexpr int HROW = 256;            // hist row in halfs (512 B)
constexpr int XROW = 40;             // stim row in halfs (80 B, 16B-aligned)

__global__ __launch_bounds__(256, 1) void rnn_kernel(const void* __restrict__ stim,
                                                     float* __restrict__ out) {
    const bool stf = sniff_f32(stim);
    const int b    = blockIdx.x;
    const int tid  = threadIdx.x;
    const int lane = tid & 63;
    const int wv   = tid >> 6;       // 0..3
    const int l15  = lane & 15;
    const int q    = lane >> 4;      // 0..3

    const float* p1 = out + OUT_P1 + (size_t)b * N1_;
    const float* p2 = out + OUT_P2 + (size_t)b * N2_;

    __shared__ alignas(16) half_t hist[(T_ + 1) * HROW];   // 131584 B
    __shared__ alignas(16) half_t stim_s[T_ * XROW];       // 20480 B

    // ---- stage stimulus: row t holds x_ext = [x_{t-1}(16), 1.0, 0 x15, pad]; row0 x = 0 --
    if (stf) {
        const float2* sp = (const float2*)stim + (size_t)b * T_ * 8;
        for (int idx = tid; idx < (T_ - 1) * 8; idx += 256) {
            const int tt = idx >> 3, pr = idx & 7;
            float2 v = sp[idx];
            half2_t h; h.x = (half_t)v.x; h.y = (half_t)v.y;
            *(half2_t*)&stim_s[(tt + 1) * XROW + pr * 2] = h;
        }
    } else {
        const u32* sp = (const u32*)((const u16*)stim + (size_t)b * T_ * I_);
        for (int idx = tid; idx < (T_ - 1) * 8; idx += 256) {
            const int tt = idx >> 3, pr = idx & 7;
            u32 u = sp[idx];
            union { u32 i; float f; } lo2, hi2;
            lo2.i = u << 16; hi2.i = u & 0xffff0000u;
            half2_t h; h.x = (half_t)lo2.f; h.y = (half_t)hi2.f;
            *(half2_t*)&stim_s[(tt + 1) * XROW + pr * 2] = h;
        }
    }
    {   // per-row constants: halfs[16]=1.0, halfs[17..39]=0; row0 x zeros; hist row0 zeros
        u32* ss = (u32*)stim_s;
        const int base = tid * (XROW / 2);   // this thread owns row `tid`
        ss[base + 8] = 0x00003C00u;          // halfs 16,17 = {1.0h, 0}
#pragma unroll
        for (int z = 9; z < XROW / 2; z++) ss[base + z] = 0u;
        if (tid < 8)   ss[tid] = 0u;                  // row0 halfs 0..15
        if (tid < 128) ((u32*)hist)[tid] = 0u;        // h0 = 0
    }

    // ---- W fragments (B-side): lane holds W[g = tile_base + l15][kt*32 + q*8 + j] --------
    halfx8 Wf[4][9];
    {
        const float* WH  = p1 + H_ * I_;               // W_hh [256][256]
        const float* BIH = p1 + H_ * I_ + H_ * H_;     // b_ih (then b_hh at +H_)
#pragma unroll
        for (int i = 0; i < 4; i++) {
            const int rr = 64 * wv + i * 16 + l15;
#pragma unroll
            for (int kt = 0; kt < 8; kt++) {
                const float4* wp = (const float4*)(WH + (size_t)rr * H_ + kt * 32 + q * 8);
                float4 r0 = wp[0], r1 = wp[1];
                halfx8 f;
                f[0] = (half_t)r0.x; f[1] = (half_t)r0.y; f[2] = (half_t)r0.z; f[3] = (half_t)r0.w;
                f[4] = (half_t)r1.x; f[5] = (half_t)r1.y; f[6] = (half_t)r1.z; f[7] = (half_t)r1.w;
                Wf[i][kt] = f;
            }
            // x-tile: k<16 -> W_ih row, k==16 -> combined bias, else 0
            halfx8 fx;
#pragma unroll
            for (int j = 0; j < 8; j++) fx[j] = (half_t)0.f;
            if (q < 2) {
                const float4* ip = (const float4*)(p1 + (size_t)rr * I_ + q * 8);
                float4 r0 = ip[0], r1 = ip[1];
                fx[0] = (half_t)r0.x; fx[1] = (half_t)r0.y; fx[2] = (half_t)r0.z; fx[3] = (half_t)r0.w;
                fx[4] = (half_t)r1.x; fx[5] = (half_t)r1.y; fx[6] = (half_t)r1.z; fx[7] = (half_t)r1.w;
            } else if (q == 2) {
                fx[0] = (half_t)(BIH[rr] + BIH[H_ + rr]);
            }
            Wf[i][8] = fx;
        }
    }
    __syncthreads();

    // ---- scan ----------------------------------------------------------------------------
    for (int t = 0; t < T_; t++) {
        halfx8 af[9];
        const half_t* hr = hist + (size_t)t * HROW + q * 8;
#pragma unroll
        for (int kt = 0; kt < 8; kt++)
            af[kt] = *(const halfx8*)(hr + kt * 32);
        af[8] = *(const halfx8*)(stim_s + (size_t)t * XROW + q * 8);

        floatx4 acc[4] = {};
#pragma unroll
        for (int kt = 0; kt < 9; kt++)
#pragma unroll
            for (int i = 0; i < 4; i++)
                acc[i] = __builtin_amdgcn_mfma_f32_16x16x32_f16(af[kt], Wf[i][kt], acc[i], 0, 0, 0);

        // all D-rows identical: reg0 on every lane = result for col l15 of that tile
        half_t* hw = hist + (size_t)(t + 1) * HROW;
#pragma unroll
        for (int i = 0; i < 4; i++) {
            const float s  = acc[i][0];
            const float e  = __expf(2.f * s);
            const float hn = 1.f - 2.f / (e + 1.f);   // tanh(s)
            if (lane < 16) {
                hw[64 * wv + i * 16 + l15] = (half_t)hn;
                if (t == T_ - 1) out[OUT_H + (size_t)b * H_ + 64 * wv + i * 16 + l15] = hn;
            }
        }
        bar_lds();   // ONE barrier/step (covers h-writes; no vmcnt drain)
    }

    // ---- post-pass: out2 = hist(T x 256) @ W_out^T via MFMA ------------------------------
    halfx8 Wo[8];
    float bo = 0.f;
    {
#pragma unroll
        for (int kt = 0; kt < 8; kt++) {
            halfx8 f;
#pragma unroll
            for (int j = 0; j < 8; j++) f[j] = (half_t)0.f;
            if (l15 < O_) {
                const float* wp = p2 + (size_t)l15 * H_ + kt * 32 + q * 8;   // 4B-aligned only
#pragma unroll
                for (int j = 0; j < 8; j++) f[j] = (half_t)wp[j];
            }
            Wo[kt] = f;
        }
        if (l15 < O_) bo = p2[O_ * H_ + l15];
    }

#pragma unroll
    for (int m = 0; m < 4; m++) {
        const int tb = (4 * wv + m) * 16;     // t' base for this M-tile
        const half_t* hr = hist + (size_t)(tb + l15 + 1) * HROW + q * 8;
        floatx4 acc = {};
#pragma unroll
        for (int kt = 0; kt < 8; kt++) {
            halfx8 a = *(const halfx8*)(hr + kt * 32);
            acc = __builtin_amdgcn_mfma_f32_16x16x32_f16(a, Wo[kt], acc, 0, 0, 0);
        }
        if (l15 < O_) {
            const int o = l15;
#pragma unroll
            for (int r = 0; r < 4; r++) {
                const int tt = tb + q * 4 + r;
                float v2 = acc[r] + bo;
                if (o < 3) out[OUT_ACT + (size_t)b * T_ * 3 + (size_t)tt * 3 + o] = 1.f / (1.f + __expf(-v2));
                else       out[OUT_BLDI + (size_t)b * T_ * 8 + (size_t)tt * 8 + (o - 3)] = v2;
            }
        }
    }
}

extern "C" void kernel_launch(void* const* d_in, const int* in_sizes, int n_in,
                              void* d_out, int out_size, void* d_ws, size_t ws_size,
                              hipStream_t stream) {
    (void)in_sizes; (void)n_in; (void)out_size; (void)d_ws; (void)ws_size;
    const void* bld  = d_in[0];
    const void* stim = d_in[1];
    const void* W1   = d_in[2];
    const void* b1   = d_in[3];
    const void* W2   = d_in[4];
    const void* b2   = d_in[5];
    float* out = (float*)d_out;
    u16* h1 = (u16*)out;   // 256x512 bf16 stash inside act region (rewritten by rnn post-pass)

    h1_kernel<<<B_, HYP, 0, stream>>>(bld, W1, b1, h1);
    gemm_kernel<<<(GN + 63) / 64, 256, 0, stream>>>(h1, W2, b2, out);
    rnn_kernel<<<B_, 256, 0, stream>>>(stim, out);
}

// Round 5
// 437.727 us; speedup vs baseline: 1.3813x; 1.0345x over previous
//
#include <hip/hip_runtime.h>

typedef unsigned short u16;
typedef unsigned int u32;
using short8   = __attribute__((ext_vector_type(8))) short;
using floatx4  = __attribute__((ext_vector_type(4))) float;
using half_t   = _Float16;
using half2_t  = __attribute__((ext_vector_type(2))) _Float16;
using halfx8   = __attribute__((ext_vector_type(8))) _Float16;

constexpr int B_ = 256, T_ = 256, I_ = 16, H_ = 256, O_ = 11;
constexpr int HYP = 512;
constexpr int N1_ = H_ * I_ + H_ * H_ + 2 * H_;   // 70144
constexpr int N2_ = O_ * H_ + O_;                 // 2827
constexpr int GN  = N1_ + N2_;                    // 72971

// d_out is float32; offsets in float elements
constexpr size_t OUT_ACT  = 0;
constexpr size_t OUT_BLDI = (size_t)B_ * T_ * 3;            // 196608
constexpr size_t OUT_H    = OUT_BLDI + (size_t)B_ * T_ * 8; // 720896
constexpr size_t OUT_P1   = OUT_H + (size_t)B_ * H_;        // 786432
constexpr size_t OUT_P2   = OUT_P1 + (size_t)B_ * N1_;      // 18743296

// Raw workgroup barrier: LDS ordering only (no vmcnt drain).
__device__ inline void bar_lds() {
    asm volatile("s_waitcnt lgkmcnt(0)\n\ts_barrier" ::: "memory");
}

__device__ inline float bf2f(u16 u) {
    union { u32 i; float f; } v; v.i = ((u32)u) << 16; return v.f;
}
__device__ inline u16 f2bf(float f) {
    u32 x = __float_as_uint(f);
    u32 r = (x + 0x7fffu + ((x >> 16) & 1u)) >> 16;   // RNE, finite inputs
    return (u16)r;
}

// Per-tensor dtype sniff (wave-uniform).
__device__ inline bool sniff_f32(const void* p) {
    const u16* w = (const u16*)p;
    const int lane = threadIdx.x & 63;
    u16 u = w[lane * 2];
    unsigned e = (u >> 7) & 0xFF;
    bool inband = (u == 0) || (e >= 77 && e <= 140);
    return __popcll(__ballot(inband)) < 56;
}

__device__ inline float ldr(const void* p, size_t i, bool f32) {
    return f32 ? ((const float*)p)[i] : bf2f(((const u16*)p)[i]);
}

// ---------------- kernel 1: h1 = relu(bld @ W1 + b1) -> bf16 stash in out[0..65536) --------
__global__ void h1_kernel(const void* __restrict__ bld, const void* __restrict__ W1,
                          const void* __restrict__ b1, u16* __restrict__ h1) {
    const bool bldf = sniff_f32(bld);
    const bool w1f  = sniff_f32(W1);
    const bool b1f  = sniff_f32(b1);
    const int b = blockIdx.x;
    const int j = threadIdx.x;
    float acc = ldr(b1, j, b1f);
#pragma unroll
    for (int k = 0; k < 8; k++)
        acc += ldr(bld, b * 8 + k, bldf) * ldr(W1, k * HYP + j, w1f);
    h1[b * HYP + j] = f2bf(fmaxf(acc, 0.f));
}

// ---------------- kernel 2: flat = h1 @ W2 + b2 -> params1/params2 (f32, d_out) ------------
// Double-buffered transposed LDS tile (2 x [64][40] u16), ONE raw barrier per K-step.
// A-fragments prefetched 1 step ahead (global, L2-resident), B prefetched 2 steps ahead:
// no load wait lands inside the compute window.
constexpr int KS_ = 32;              // k per stage step
constexpr int NST = HYP / KS_;       // 16
constexpr int TKP = 40;              // padded k-dim in u16 (32 + 8) -> 80B rows

template<bool W2F32>
__device__ void gemm_body(const u16* __restrict__ A, const void* __restrict__ Bm,
                          const void* __restrict__ b2, bool b2f,
                          float* __restrict__ out) {
    __shared__ alignas(16) u16 tileT[2][64][TKP];   // 10240 B

    const int nb   = blockIdx.x * 64;
    const int tid  = threadIdx.x;
    const int lane = tid & 63;
    const int wid  = tid >> 6;
    const int l15  = lane & 15;
    const int q    = lane >> 4;

    int  col[4]; bool cv[4];
#pragma unroll
    for (int j = 0; j < 4; j++) {
        int c = nb + j * 16 + l15;
        cv[j]  = (c < GN);
        col[j] = cv[j] ? c : (GN - 1);
    }

    const u16* ap[4];
#pragma unroll
    for (int i = 0; i < 4; i++)
        ap[i] = A + (wid * 64 + i * 16 + l15) * HYP + q * 8;

    const int scol_i = tid & 63;
    const int kq     = tid >> 6;          // 0..3
    int gc = nb + scol_i;
    if (gc >= GN) gc = GN - 1;            // tail clamp (values masked at store)
    const size_t colOff = (size_t)gc;

    float pfw[8]; u16 pbw[8];             // B data for the tile written NEXT step
    short8 afc[4];                        // A fragments for the CURRENT step

    // ---- prologue: stage B(0); start B(1) + A(0); one barrier -----------------------------
    {
        float t0[8]; u16 t1[8];
#pragma unroll
        for (int e = 0; e < 8; e++) {
            const size_t ro = (size_t)(kq * 8 + e) * (size_t)GN + colOff;
            if constexpr (W2F32) t0[e] = ((const float*)Bm)[ro];
            else                 t1[e] = ((const u16*)Bm)[ro];
        }
        short8 wv8;
#pragma unroll
        for (int e = 0; e < 8; e++) {
            if constexpr (W2F32) wv8[e] = (short)f2bf(t0[e]);
            else                 wv8[e] = (short)t1[e];
        }
        *(short8*)&tileT[0][scol_i][kq * 8] = wv8;
    }
#pragma unroll
    for (int e = 0; e < 8; e++) {
        const size_t ro = (size_t)(KS_ + kq * 8 + e) * (size_t)GN + colOff;
        if constexpr (W2F32) pfw[e] = ((const float*)Bm)[ro];
        else                 pbw[e] = ((const u16*)Bm)[ro];
    }
#pragma unroll
    for (int i = 0; i < 4; i++) afc[i] = *(const short8*)(ap[i]);
    bar_lds();

    floatx4 acc[4][4] = {};

#pragma unroll
    for (int ks = 0; ks < NST; ks++) {
        const int cur = ks & 1;

        short8 bfr[4];
#pragma unroll
        for (int j = 0; j < 4; j++)
            bfr[j] = *(const short8*)&tileT[cur][j * 16 + l15][q * 8];

        short8 afn[4];
        if (ks + 1 < NST) {
#pragma unroll
            for (int i = 0; i < 4; i++)
                afn[i] = *(const short8*)(ap[i] + (ks + 1) * KS_);
        }
        float pfn[8]; u16 pbn[8];
        if (ks + 2 < NST) {
#pragma unroll
            for (int e = 0; e < 8; e++) {
                const size_t ro = (size_t)((ks + 2) * KS_ + kq * 8 + e) * (size_t)GN + colOff;
                if constexpr (W2F32) pfn[e] = ((const float*)Bm)[ro];
                else                 pbn[e] = ((const u16*)Bm)[ro];
            }
        }
        if (ks + 1 < NST) {   // write tile ks+1 into the other buffer (no reader this step)
            short8 wv8;
#pragma unroll
            for (int e = 0; e < 8; e++) {
                if constexpr (W2F32) wv8[e] = (short)f2bf(pfw[e]);
                else                 wv8[e] = (short)pbw[e];
            }
            *(short8*)&tileT[cur ^ 1][scol_i][kq * 8] = wv8;
        }

#pragma unroll
        for (int i = 0; i < 4; i++)
#pragma unroll
            for (int j = 0; j < 4; j++)
                acc[i][j] = __builtin_amdgcn_mfma_f32_16x16x32_bf16(afc[i], bfr[j], acc[i][j], 0, 0, 0);
        bar_lds();   // writes of tile ks+1 visible; reads of tile ks drained

#pragma unroll
        for (int i = 0; i < 4; i++) afc[i] = afn[i];
#pragma unroll
        for (int e = 0; e < 8; e++) {
            if constexpr (W2F32) pfw[e] = pfn[e];
            else                 pbw[e] = pbn[e];
        }
    }

    const bool isP2 = (nb >= N1_);   // N1_ multiple of 64 -> no straddle
#pragma unroll
    for (int j = 0; j < 4; j++) {
        const float bias = ldr(b2, col[j], b2f);
#pragma unroll
        for (int i = 0; i < 4; i++) {
            const int mbase = wid * 64 + i * 16 + q * 4;
#pragma unroll
            for (int r = 0; r < 4; r++) {
                if (cv[j]) {
                    const float v = acc[i][j][r] + bias;
                    const int m = mbase + r;
                    size_t dst;
                    if (isP2) dst = OUT_P2 + (size_t)m * N2_ + (size_t)(col[j] - N1_);
                    else      dst = OUT_P1 + (size_t)m * N1_ + (size_t)col[j];
                    out[dst] = v;
                }
            }
        }
    }
}
__global__ __launch_bounds__(256) void gemm_kernel(const u16* A, const void* Bm,
                                                   const void* b2, float* out) {
    const bool w2f = sniff_f32(Bm);
    const bool b2f = sniff_f32(b2);
    if (w2f) gemm_body<true>(A, Bm, b2, b2f, out);
    else     gemm_body<false>(A, Bm, b2, b2f, out);
}

// ---------------- kernel 3: per-batch RNN scan via MFMA, 8 waves --------------------------
// 512 thr = 8 waves = 2 waves/SIMD: sibling wave's MFMA issue hides ds_read latency,
// tanh and barrier cost (the r4 failure mode at 1 wave/SIMD).
// Wave wv owns g in [32*wv, 32*wv+32): 2 g-tiles -> 18 MFMA/step/wave.
// A-operand (h) broadcast-read: every A-row holds the same h vector; k-reduction inside
// MFMA. Bias folds in via x_ext slot16 = 1.0, B slot16 = b_ih+b_hh.
constexpr int HROW = 256;            // hist row in halfs (512 B)
constexpr int XROW = 40;             // stim row in halfs (80 B, 16B-aligned)

__global__ __launch_bounds__(512, 1) void rnn_kernel(const void* __restrict__ stim,
                                                     float* __restrict__ out) {
    const bool stf = sniff_f32(stim);
    const int b    = blockIdx.x;
    const int tid  = threadIdx.x;
    const int lane = tid & 63;
    const int wv   = tid >> 6;       // 0..7
    const int l15  = lane & 15;
    const int q    = lane >> 4;      // 0..3

    const float* p1 = out + OUT_P1 + (size_t)b * N1_;
    const float* p2 = out + OUT_P2 + (size_t)b * N2_;

    __shared__ alignas(16) half_t hist[(T_ + 1) * HROW];   // 131584 B
    __shared__ alignas(16) half_t stim_s[T_ * XROW];       // 20480 B

    // ---- stage stimulus: row t holds x_ext = [x_{t-1}(16), 1.0, 0 x15, pad]; row0 x = 0 --
    if (stf) {
        const float2* sp = (const float2*)stim + (size_t)b * T_ * 8;
        for (int idx = tid; idx < (T_ - 1) * 8; idx += 512) {
            const int tt = idx >> 3, pr = idx & 7;
            float2 v = sp[idx];
            half2_t h; h.x = (half_t)v.x; h.y = (half_t)v.y;
            *(half2_t*)&stim_s[(tt + 1) * XROW + pr * 2] = h;
        }
    } else {
        const u32* sp = (const u32*)((const u16*)stim + (size_t)b * T_ * I_);
        for (int idx = tid; idx < (T_ - 1) * 8; idx += 512) {
            const int tt = idx >> 3, pr = idx & 7;
            u32 u = sp[idx];
            union { u32 i; float f; } lo2, hi2;
            lo2.i = u << 16; hi2.i = u & 0xffff0000u;
            half2_t h; h.x = (half_t)lo2.f; h.y = (half_t)hi2.f;
            *(half2_t*)&stim_s[(tt + 1) * XROW + pr * 2] = h;
        }
    }
    {   // per-row constants: halfs[16]=1.0, halfs[17..39]=0; row0 x zeros; hist row0 zeros
        u32* ss = (u32*)stim_s;
        if (tid < 256) {
            const int base = tid * (XROW / 2);   // this thread owns row `tid`
            ss[base + 8] = 0x00003C00u;          // halfs 16,17 = {1.0h, 0}
#pragma unroll
            for (int z = 9; z < XROW / 2; z++) ss[base + z] = 0u;
        }
        if (tid < 8)   ss[tid] = 0u;                  // row0 halfs 0..15
        if (tid < 128) ((u32*)hist)[tid] = 0u;        // h0 = 0
    }

    // ---- W fragments (B-side): lane holds W[g = 32*wv + it*16 + l15][kt*32 + q*8 + j] ----
    halfx8 Wf[2][9];
    {
        const float* WH  = p1 + H_ * I_;               // W_hh [256][256]
        const float* BIH = p1 + H_ * I_ + H_ * H_;     // b_ih (then b_hh at +H_)
#pragma unroll
        for (int it = 0; it < 2; it++) {
            const int rr = 32 * wv + it * 16 + l15;
#pragma unroll
            for (int kt = 0; kt < 8; kt++) {
                const float4* wp = (const float4*)(WH + (size_t)rr * H_ + kt * 32 + q * 8);
                float4 r0 = wp[0], r1 = wp[1];
                halfx8 f;
                f[0] = (half_t)r0.x; f[1] = (half_t)r0.y; f[2] = (half_t)r0.z; f[3] = (half_t)r0.w;
                f[4] = (half_t)r1.x; f[5] = (half_t)r1.y; f[6] = (half_t)r1.z; f[7] = (half_t)r1.w;
                Wf[it][kt] = f;
            }
            // x-tile: k<16 -> W_ih row, k==16 -> combined bias, else 0
            halfx8 fx;
#pragma unroll
            for (int j = 0; j < 8; j++) fx[j] = (half_t)0.f;
            if (q < 2) {
                const float4* ip = (const float4*)(p1 + (size_t)rr * I_ + q * 8);
                float4 r0 = ip[0], r1 = ip[1];
                fx[0] = (half_t)r0.x; fx[1] = (half_t)r0.y; fx[2] = (half_t)r0.z; fx[3] = (half_t)r0.w;
                fx[4] = (half_t)r1.x; fx[5] = (half_t)r1.y; fx[6] = (half_t)r1.z; fx[7] = (half_t)r1.w;
            } else if (q == 2) {
                fx[0] = (half_t)(BIH[rr] + BIH[H_ + rr]);
            }
            Wf[it][8] = fx;
        }
    }
    __syncthreads();

    // ---- scan ----------------------------------------------------------------------------
    for (int t = 0; t < T_; t++) {
        halfx8 af[9];
        const half_t* hr = hist + (size_t)t * HROW + q * 8;
#pragma unroll
        for (int kt = 0; kt < 8; kt++)
            af[kt] = *(const halfx8*)(hr + kt * 32);
        af[8] = *(const halfx8*)(stim_s + (size_t)t * XROW + q * 8);

        floatx4 acc[2] = {};
#pragma unroll
        for (int kt = 0; kt < 9; kt++) {
            acc[0] = __builtin_amdgcn_mfma_f32_16x16x32_f16(af[kt], Wf[0][kt], acc[0], 0, 0, 0);
            acc[1] = __builtin_amdgcn_mfma_f32_16x16x32_f16(af[kt], Wf[1][kt], acc[1], 0, 0, 0);
        }

        // all D-rows identical: reg0 on every lane = result for col l15 of that tile
        half_t* hw = hist + (size_t)(t + 1) * HROW;
#pragma unroll
        for (int it = 0; it < 2; it++) {
            const float s  = acc[it][0];
            const float e  = __expf(2.f * s);
            const float hn = 1.f - 2.f / (e + 1.f);   // tanh(s)
            if (lane < 16) {
                hw[32 * wv + it * 16 + l15] = (half_t)hn;
                if (t == T_ - 1) out[OUT_H + (size_t)b * H_ + 32 * wv + it * 16 + l15] = hn;
            }
        }
        bar_lds();   // ONE barrier/step (covers h-writes; no vmcnt drain)
    }

    // ---- post-pass: out2 = hist(T x 256) @ W_out^T via MFMA ------------------------------
    halfx8 Wo[8];
    float bo = 0.f;
    {
#pragma unroll
        for (int kt = 0; kt < 8; kt++) {
            halfx8 f;
#pragma unroll
            for (int j = 0; j < 8; j++) f[j] = (half_t)0.f;
            if (l15 < O_) {
                const float* wp = p2 + (size_t)l15 * H_ + kt * 32 + q * 8;   // 4B-aligned only
#pragma unroll
                for (int j = 0; j < 8; j++) f[j] = (half_t)wp[j];
            }
            Wo[kt] = f;
        }
        if (l15 < O_) bo = p2[O_ * H_ + l15];
    }

#pragma unroll
    for (int m = 0; m < 2; m++) {
        const int tb = (2 * wv + m) * 16;     // t' base for this M-tile
        const half_t* hr = hist + (size_t)(tb + l15 + 1) * HROW + q * 8;
        floatx4 acc = {};
#pragma unroll
        for (int kt = 0; kt < 8; kt++) {
            halfx8 a = *(const halfx8*)(hr + kt * 32);
            acc = __builtin_amdgcn_mfma_f32_16x16x32_f16(a, Wo[kt], acc, 0, 0, 0);
        }
        if (l15 < O_) {
            const int o = l15;
#pragma unroll
            for (int r = 0; r < 4; r++) {
                const int tt = tb + q * 4 + r;
                float v2 = acc[r] + bo;
                if (o < 3) out[OUT_ACT + (size_t)b * T_ * 3 + (size_t)tt * 3 + o] = 1.f / (1.f + __expf(-v2));
                else       out[OUT_BLDI + (size_t)b * T_ * 8 + (size_t)tt * 8 + (o - 3)] = v2;
            }
        }
    }
}

extern "C" void kernel_launch(void* const* d_in, const int* in_sizes, int n_in,
                              void* d_out, int out_size, void* d_ws, size_t ws_size,
                              hipStream_t stream) {
    (void)in_sizes; (void)n_in; (void)out_size; (void)d_ws; (void)ws_size;
    const void* bld  = d_in[0];
    const void* stim = d_in[1];
    const void* W1   = d_in[2];
    const void* b1   = d_in[3];
    const void* W2   = d_in[4];
    const void* b2   = d_in[5];
    float* out = (float*)d_out;
    u16* h1 = (u16*)out;   // 256x512 bf16 stash inside act region (rewritten by rnn post-pass)

    h1_kernel<<<B_, HYP, 0, stream>>>(bld, W1, b1, h1);
    gemm_kernel<<<(GN + 63) / 64, 256, 0, stream>>>(h1, W2, b2, out);
    rnn_kernel<<<B_, 512, 0, stream>>>(stim, out);
}

// Round 6
// 417.713 us; speedup vs baseline: 1.4474x; 1.0479x over previous
//
#include <hip/hip_runtime.h>

typedef unsigned short u16;
typedef unsigned int u32;
using short8   = __attribute__((ext_vector_type(8))) short;
using floatx4  = __attribute__((ext_vector_type(4))) float;
using half_t   = _Float16;
using half2_t  = __attribute__((ext_vector_type(2))) _Float16;
using halfx8   = __attribute__((ext_vector_type(8))) _Float16;

constexpr int B_ = 256, T_ = 256, I_ = 16, H_ = 256, O_ = 11;
constexpr int HYP = 512;
constexpr int N1_ = H_ * I_ + H_ * H_ + 2 * H_;   // 70144
constexpr int N2_ = O_ * H_ + O_;                 // 2827
constexpr int GN  = N1_ + N2_;                    // 72971

// d_out is float32; offsets in float elements
constexpr size_t OUT_ACT  = 0;
constexpr size_t OUT_BLDI = (size_t)B_ * T_ * 3;            // 196608
constexpr size_t OUT_H    = OUT_BLDI + (size_t)B_ * T_ * 8; // 720896
constexpr size_t OUT_P1   = OUT_H + (size_t)B_ * H_;        // 786432
constexpr size_t OUT_P2   = OUT_P1 + (size_t)B_ * N1_;      // 18743296

// Raw workgroup barrier: LDS ordering only (no vmcnt drain).
__device__ inline void bar_lds() {
    asm volatile("s_waitcnt lgkmcnt(0)\n\ts_barrier" ::: "memory");
}

__device__ inline float bf2f(u16 u) {
    union { u32 i; float f; } v; v.i = ((u32)u) << 16; return v.f;
}
__device__ inline u16 f2bf(float f) {
    u32 x = __float_as_uint(f);
    u32 r = (x + 0x7fffu + ((x >> 16) & 1u)) >> 16;   // RNE, finite inputs
    return (u16)r;
}

// Per-tensor dtype sniff (wave-uniform).
__device__ inline bool sniff_f32(const void* p) {
    const u16* w = (const u16*)p;
    const int lane = threadIdx.x & 63;
    u16 u = w[lane * 2];
    unsigned e = (u >> 7) & 0xFF;
    bool inband = (u == 0) || (e >= 77 && e <= 140);
    return __popcll(__ballot(inband)) < 56;
}

__device__ inline float ldr(const void* p, size_t i, bool f32) {
    return f32 ? ((const float*)p)[i] : bf2f(((const u16*)p)[i]);
}

// ---------------- kernel 1: h1 = relu(bld @ W1 + b1) -> bf16 stash in out[0..65536) --------
__global__ void h1_kernel(const void* __restrict__ bld, const void* __restrict__ W1,
                          const void* __restrict__ b1, u16* __restrict__ h1) {
    const bool bldf = sniff_f32(bld);
    const bool w1f  = sniff_f32(W1);
    const bool b1f  = sniff_f32(b1);
    const int b = blockIdx.x;
    const int j = threadIdx.x;
    float acc = ldr(b1, j, b1f);
#pragma unroll
    for (int k = 0; k < 8; k++)
        acc += ldr(bld, b * 8 + k, bldf) * ldr(W1, k * HYP + j, w1f);
    h1[b * HYP + j] = f2bf(fmaxf(acc, 0.f));
}

// ---------------- kernel 2: flat = h1 @ W2 + b2 -> params1/params2 (f32, d_out) ------------
// Double-buffered transposed LDS tile (2 x [64][40] u16), ONE raw barrier per K-step.
// A-fragments prefetched 1 step ahead (global, L2-resident), B prefetched 2 steps ahead.
// (FROZEN this round for clean rnn A/B attribution.)
constexpr int KS_ = 32;              // k per stage step
constexpr int NST = HYP / KS_;       // 16
constexpr int TKP = 40;              // padded k-dim in u16 (32 + 8) -> 80B rows

template<bool W2F32>
__device__ void gemm_body(const u16* __restrict__ A, const void* __restrict__ Bm,
                          const void* __restrict__ b2, bool b2f,
                          float* __restrict__ out) {
    __shared__ alignas(16) u16 tileT[2][64][TKP];   // 10240 B

    const int nb   = blockIdx.x * 64;
    const int tid  = threadIdx.x;
    const int lane = tid & 63;
    const int wid  = tid >> 6;
    const int l15  = lane & 15;
    const int q    = lane >> 4;

    int  col[4]; bool cv[4];
#pragma unroll
    for (int j = 0; j < 4; j++) {
        int c = nb + j * 16 + l15;
        cv[j]  = (c < GN);
        col[j] = cv[j] ? c : (GN - 1);
    }

    const u16* ap[4];
#pragma unroll
    for (int i = 0; i < 4; i++)
        ap[i] = A + (wid * 64 + i * 16 + l15) * HYP + q * 8;

    const int scol_i = tid & 63;
    const int kq     = tid >> 6;          // 0..3
    int gc = nb + scol_i;
    if (gc >= GN) gc = GN - 1;            // tail clamp (values masked at store)
    const size_t colOff = (size_t)gc;

    float pfw[8]; u16 pbw[8];             // B data for the tile written NEXT step
    short8 afc[4];                        // A fragments for the CURRENT step

    // ---- prologue: stage B(0); start B(1) + A(0); one barrier -----------------------------
    {
        float t0[8]; u16 t1[8];
#pragma unroll
        for (int e = 0; e < 8; e++) {
            const size_t ro = (size_t)(kq * 8 + e) * (size_t)GN + colOff;
            if constexpr (W2F32) t0[e] = ((const float*)Bm)[ro];
            else                 t1[e] = ((const u16*)Bm)[ro];
        }
        short8 wv8;
#pragma unroll
        for (int e = 0; e < 8; e++) {
            if constexpr (W2F32) wv8[e] = (short)f2bf(t0[e]);
            else                 wv8[e] = (short)t1[e];
        }
        *(short8*)&tileT[0][scol_i][kq * 8] = wv8;
    }
#pragma unroll
    for (int e = 0; e < 8; e++) {
        const size_t ro = (size_t)(KS_ + kq * 8 + e) * (size_t)GN + colOff;
        if constexpr (W2F32) pfw[e] = ((const float*)Bm)[ro];
        else                 pbw[e] = ((const u16*)Bm)[ro];
    }
#pragma unroll
    for (int i = 0; i < 4; i++) afc[i] = *(const short8*)(ap[i]);
    bar_lds();

    floatx4 acc[4][4] = {};

#pragma unroll
    for (int ks = 0; ks < NST; ks++) {
        const int cur = ks & 1;

        short8 bfr[4];
#pragma unroll
        for (int j = 0; j < 4; j++)
            bfr[j] = *(const short8*)&tileT[cur][j * 16 + l15][q * 8];

        short8 afn[4];
        if (ks + 1 < NST) {
#pragma unroll
            for (int i = 0; i < 4; i++)
                afn[i] = *(const short8*)(ap[i] + (ks + 1) * KS_);
        }
        float pfn[8]; u16 pbn[8];
        if (ks + 2 < NST) {
#pragma unroll
            for (int e = 0; e < 8; e++) {
                const size_t ro = (size_t)((ks + 2) * KS_ + kq * 8 + e) * (size_t)GN + colOff;
                if constexpr (W2F32) pfn[e] = ((const float*)Bm)[ro];
                else                 pbn[e] = ((const u16*)Bm)[ro];
            }
        }
        if (ks + 1 < NST) {   // write tile ks+1 into the other buffer (no reader this step)
            short8 wv8;
#pragma unroll
            for (int e = 0; e < 8; e++) {
                if constexpr (W2F32) wv8[e] = (short)f2bf(pfw[e]);
                else                 wv8[e] = (short)pbw[e];
            }
            *(short8*)&tileT[cur ^ 1][scol_i][kq * 8] = wv8;
        }

#pragma unroll
        for (int i = 0; i < 4; i++)
#pragma unroll
            for (int j = 0; j < 4; j++)
                acc[i][j] = __builtin_amdgcn_mfma_f32_16x16x32_bf16(afc[i], bfr[j], acc[i][j], 0, 0, 0);
        bar_lds();   // writes of tile ks+1 visible; reads of tile ks drained

#pragma unroll
        for (int i = 0; i < 4; i++) afc[i] = afn[i];
#pragma unroll
        for (int e = 0; e < 8; e++) {
            if constexpr (W2F32) pfw[e] = pfn[e];
            else                 pbw[e] = pbn[e];
        }
    }

    const bool isP2 = (nb >= N1_);   // N1_ multiple of 64 -> no straddle
#pragma unroll
    for (int j = 0; j < 4; j++) {
        const float bias = ldr(b2, col[j], b2f);
#pragma unroll
        for (int i = 0; i < 4; i++) {
            const int mbase = wid * 64 + i * 16 + q * 4;
#pragma unroll
            for (int r = 0; r < 4; r++) {
                if (cv[j]) {
                    const float v = acc[i][j][r] + bias;
                    const int m = mbase + r;
                    size_t dst;
                    if (isP2) dst = OUT_P2 + (size_t)m * N2_ + (size_t)(col[j] - N1_);
                    else      dst = OUT_P1 + (size_t)m * N1_ + (size_t)col[j];
                    out[dst] = v;
                }
            }
        }
    }
}
__global__ __launch_bounds__(256) void gemm_kernel(const u16* A, const void* Bm,
                                                   const void* b2, float* out) {
    const bool w2f = sniff_f32(Bm);
    const bool b2f = sniff_f32(b2);
    if (w2f) gemm_body<true>(A, Bm, b2, b2f, out);
    else     gemm_body<false>(A, Bm, b2, b2f, out);
}

// ---------------- kernel 3: per-batch RNN scan via MFMA, 8 waves --------------------------
// v6: x_proj precomputed via one-time MFMA pass into hist[t+1] slots (input-only data!);
// scan step t reads the xp scalar from hist[t+1] and overwrites it in place with h_{t+1}
// (same lane, same addr, wave-ordered). Per step/wave: 8 ds_read_b128 + 16 MFMA (setprio-
// wrapped) + 1 u16 read + tanh + 1 b16 write + ONE raw barrier.
constexpr int HROW = 256;            // hist row in halfs (512 B)
constexpr int XROW = 40;             // stim row in halfs (80 B, 16B-aligned)

__global__ __launch_bounds__(512, 1) void rnn_kernel(const void* __restrict__ stim,
                                                     float* __restrict__ out) {
    const bool stf = sniff_f32(stim);
    const int b    = blockIdx.x;
    const int tid  = threadIdx.x;
    const int lane = tid & 63;
    const int wv   = tid >> 6;       // 0..7
    const int l15  = lane & 15;
    const int q    = lane >> 4;      // 0..3

    const float* p1 = out + OUT_P1 + (size_t)b * N1_;
    const float* p2 = out + OUT_P2 + (size_t)b * N2_;

    __shared__ alignas(16) half_t hist[(T_ + 1) * HROW];   // 131584 B
    __shared__ alignas(16) half_t stim_s[T_ * XROW];       // 20480 B

    // ---- stage stimulus: row t holds x_ext = [x_{t-1}(16), 1.0, 0 x23]; row0 x = 0 -------
    if (stf) {
        const float2* sp = (const float2*)stim + (size_t)b * T_ * 8;
        for (int idx = tid; idx < (T_ - 1) * 8; idx += 512) {
            const int tt = idx >> 3, pr = idx & 7;
            float2 v = sp[idx];
            half2_t h; h.x = (half_t)v.x; h.y = (half_t)v.y;
            *(half2_t*)&stim_s[(tt + 1) * XROW + pr * 2] = h;
        }
    } else {
        const u32* sp = (const u32*)((const u16*)stim + (size_t)b * T_ * I_);
        for (int idx = tid; idx < (T_ - 1) * 8; idx += 512) {
            const int tt = idx >> 3, pr = idx & 7;
            u32 u = sp[idx];
            union { u32 i; float f; } lo2, hi2;
            lo2.i = u << 16; hi2.i = u & 0xffff0000u;
            half2_t h; h.x = (half_t)lo2.f; h.y = (half_t)hi2.f;
            *(half2_t*)&stim_s[(tt + 1) * XROW + pr * 2] = h;
        }
    }
    {   // per-row constants: halfs[16]=1.0, halfs[17..39]=0; row0 x zeros; hist row0 zeros
        u32* ss = (u32*)stim_s;
        if (tid < 256) {
            const int base = tid * (XROW / 2);   // this thread owns row `tid`
            ss[base + 8] = 0x00003C00u;          // halfs 16,17 = {1.0h, 0}
#pragma unroll
            for (int z = 9; z < XROW / 2; z++) ss[base + z] = 0u;
        }
        if (tid < 8)   ss[tid] = 0u;                  // row0 halfs 0..15
        if (tid < 128) ((u32*)hist)[tid] = 0u;        // h0 = 0
    }

    // ---- W fragments (B-side): lane holds W[g = 32*wv + it*16 + l15][kt*32 + q*8 + j] ----
    halfx8 Wf[2][8];   // W_hh only (scan)
    halfx8 Wx[2];      // x-tile: W_ih row | combined bias (precompute only)
    {
        const float* WH  = p1 + H_ * I_;               // W_hh [256][256]
        const float* BIH = p1 + H_ * I_ + H_ * H_;     // b_ih (then b_hh at +H_)
#pragma unroll
        for (int it = 0; it < 2; it++) {
            const int rr = 32 * wv + it * 16 + l15;
#pragma unroll
            for (int kt = 0; kt < 8; kt++) {
                const float4* wp = (const float4*)(WH + (size_t)rr * H_ + kt * 32 + q * 8);
                float4 r0 = wp[0], r1 = wp[1];
                halfx8 f;
                f[0] = (half_t)r0.x; f[1] = (half_t)r0.y; f[2] = (half_t)r0.z; f[3] = (half_t)r0.w;
                f[4] = (half_t)r1.x; f[5] = (half_t)r1.y; f[6] = (half_t)r1.z; f[7] = (half_t)r1.w;
                Wf[it][kt] = f;
            }
            // x-tile: k<16 -> W_ih row, k==16 -> combined bias, else 0
            halfx8 fx;
#pragma unroll
            for (int j = 0; j < 8; j++) fx[j] = (half_t)0.f;
            if (q < 2) {
                const float4* ip = (const float4*)(p1 + (size_t)rr * I_ + q * 8);
                float4 r0 = ip[0], r1 = ip[1];
                fx[0] = (half_t)r0.x; fx[1] = (half_t)r0.y; fx[2] = (half_t)r0.z; fx[3] = (half_t)r0.w;
                fx[4] = (half_t)r1.x; fx[5] = (half_t)r1.y; fx[6] = (half_t)r1.z; fx[7] = (half_t)r1.w;
            } else if (q == 2) {
                fx[0] = (half_t)(BIH[rr] + BIH[H_ + rr]);
            }
            Wx[it] = fx;
        }
    }
    __syncthreads();   // stim_s + hist row0 visible

    // ---- precompute x_proj[t] -> hist[t+1] (one-time MFMA pass over all t) ---------------
    // A-tile tm: A[row=l15][k=q*8+j] = stim_s[(16tm+l15)*XROW + q*8+j]  (x_ext rows)
    // D row = 16tm + 4q + r -> write hist[(trow+1)*HROW + g]
#pragma unroll
    for (int tm = 0; tm < 16; tm++) {
        halfx8 ax = *(const halfx8*)(stim_s + (size_t)(16 * tm + l15) * XROW + q * 8);
        floatx4 xa0 = __builtin_amdgcn_mfma_f32_16x16x32_f16(ax, Wx[0], floatx4{}, 0, 0, 0);
        floatx4 xa1 = __builtin_amdgcn_mfma_f32_16x16x32_f16(ax, Wx[1], floatx4{}, 0, 0, 0);
#pragma unroll
        for (int r = 0; r < 4; r++) {
            const int trow = 16 * tm + 4 * q + r;
            hist[(size_t)(trow + 1) * HROW + 32 * wv + l15]      = (half_t)xa0[r];
            hist[(size_t)(trow + 1) * HROW + 32 * wv + 16 + l15] = (half_t)xa1[r];
        }
    }
    __syncthreads();   // xp slots visible to all waves

    // ---- scan ----------------------------------------------------------------------------
    const int g32 = 32 * wv + (lane & 31);
    for (int t = 0; t < T_; t++) {
        halfx8 af[8];
        const half_t* hr = hist + (size_t)t * HROW + q * 8;
#pragma unroll
        for (int kt = 0; kt < 8; kt++)
            af[kt] = *(const halfx8*)(hr + kt * 32);
        const float xp = (float)hist[(size_t)(t + 1) * HROW + g32];   // xp slot (pre-h)

        floatx4 acc0 = {}, acc1 = {};
        __builtin_amdgcn_s_setprio(1);
#pragma unroll
        for (int kt = 0; kt < 8; kt++) {
            acc0 = __builtin_amdgcn_mfma_f32_16x16x32_f16(af[kt], Wf[0][kt], acc0, 0, 0, 0);
            acc1 = __builtin_amdgcn_mfma_f32_16x16x32_f16(af[kt], Wf[1][kt], acc1, 0, 0, 0);
        }
        __builtin_amdgcn_s_setprio(0);

        if (lane < 32) {
            const float s  = ((lane < 16) ? acc0[0] : acc1[0]) + xp;   // col = lane&15
            const float e  = __expf(2.f * s);
            const float hn = 1.f - 2.f / (e + 1.f);   // tanh(s)
            hist[(size_t)(t + 1) * HROW + g32] = (half_t)hn;           // overwrite xp slot
            if (t == T_ - 1) out[OUT_H + (size_t)b * H_ + g32] = hn;
        }
        bar_lds();   // ONE barrier/step (covers h-writes; no vmcnt drain)
    }

    // ---- post-pass: out2 = hist(T x 256) @ W_out^T via MFMA ------------------------------
    halfx8 Wo[8];
    float bo = 0.f;
    {
#pragma unroll
        for (int kt = 0; kt < 8; kt++) {
            halfx8 f;
#pragma unroll
            for (int j = 0; j < 8; j++) f[j] = (half_t)0.f;
            if (l15 < O_) {
                const float* wp = p2 + (size_t)l15 * H_ + kt * 32 + q * 8;   // 4B-aligned only
#pragma unroll
                for (int j = 0; j < 8; j++) f[j] = (half_t)wp[j];
            }
            Wo[kt] = f;
        }
        if (l15 < O_) bo = p2[O_ * H_ + l15];
    }

#pragma unroll
    for (int m = 0; m < 2; m++) {
        const int tb = (2 * wv + m) * 16;     // t' base for this M-tile
        const half_t* hr = hist + (size_t)(tb + l15 + 1) * HROW + q * 8;
        floatx4 acc = {};
#pragma unroll
        for (int kt = 0; kt < 8; kt++) {
            halfx8 a = *(const halfx8*)(hr + kt * 32);
            acc = __builtin_amdgcn_mfma_f32_16x16x32_f16(a, Wo[kt], acc, 0, 0, 0);
        }
        if (l15 < O_) {
            const int o = l15;
#pragma unroll
            for (int r = 0; r < 4; r++) {
                const int tt = tb + q * 4 + r;
                float v2 = acc[r] + bo;
                if (o < 3) out[OUT_ACT + (size_t)b * T_ * 3 + (size_t)tt * 3 + o] = 1.f / (1.f + __expf(-v2));
                else       out[OUT_BLDI + (size_t)b * T_ * 8 + (size_t)tt * 8 + (o - 3)] = v2;
            }
        }
    }
}

extern "C" void kernel_launch(void* const* d_in, const int* in_sizes, int n_in,
                              void* d_out, int out_size, void* d_ws, size_t ws_size,
                              hipStream_t stream) {
    (void)in_sizes; (void)n_in; (void)out_size; (void)d_ws; (void)ws_size;
    const void* bld  = d_in[0];
    const void* stim = d_in[1];
    const void* W1   = d_in[2];
    const void* b1   = d_in[3];
    const void* W2   = d_in[4];
    const void* b2   = d_in[5];
    float* out = (float*)d_out;
    u16* h1 = (u16*)out;   // 256x512 bf16 stash inside act region (rewritten by rnn post-pass)

    h1_kernel<<<B_, HYP, 0, stream>>>(bld, W1, b1, h1);
    gemm_kernel<<<(GN + 63) / 64, 256, 0, stream>>>(h1, W2, b2, out);
    rnn_kernel<<<B_, 512, 0, stream>>>(stim, out);
}

// Round 7
// 414.222 us; speedup vs baseline: 1.4596x; 1.0084x over previous
//
#include <hip/hip_runtime.h>

typedef unsigned short u16;
typedef unsigned int u32;
using short8   = __attribute__((ext_vector_type(8))) short;
using floatx4  = __attribute__((ext_vector_type(4))) float;
using half_t   = _Float16;
using half2_t  = __attribute__((ext_vector_type(2))) _Float16;
using halfx8   = __attribute__((ext_vector_type(8))) _Float16;

constexpr int B_ = 256, T_ = 256, I_ = 16, H_ = 256, O_ = 11;
constexpr int HYP = 512;
constexpr int N1_ = H_ * I_ + H_ * H_ + 2 * H_;   // 70144
constexpr int N2_ = O_ * H_ + O_;                 // 2827
constexpr int GN  = N1_ + N2_;                    // 72971

// d_out is float32; offsets in float elements
constexpr size_t OUT_ACT  = 0;
constexpr size_t OUT_BLDI = (size_t)B_ * T_ * 3;            // 196608
constexpr size_t OUT_H    = OUT_BLDI + (size_t)B_ * T_ * 8; // 720896
constexpr size_t OUT_P1   = OUT_H + (size_t)B_ * H_;        // 786432
constexpr size_t OUT_P2   = OUT_P1 + (size_t)B_ * N1_;      // 18743296

// Raw workgroup barrier: LDS ordering only (no vmcnt drain).
__device__ inline void bar_lds() {
    asm volatile("s_waitcnt lgkmcnt(0)\n\ts_barrier" ::: "memory");
}

__device__ inline float bf2f(u16 u) {
    union { u32 i; float f; } v; v.i = ((u32)u) << 16; return v.f;
}
__device__ inline u16 f2bf(float f) {
    u32 x = __float_as_uint(f);
    u32 r = (x + 0x7fffu + ((x >> 16) & 1u)) >> 16;   // RNE, finite inputs
    return (u16)r;
}

// Per-tensor dtype sniff (wave-uniform).
__device__ inline bool sniff_f32(const void* p) {
    const u16* w = (const u16*)p;
    const int lane = threadIdx.x & 63;
    u16 u = w[lane * 2];
    unsigned e = (u >> 7) & 0xFF;
    bool inband = (u == 0) || (e >= 77 && e <= 140);
    return __popcll(__ballot(inband)) < 56;
}

__device__ inline float ldr(const void* p, size_t i, bool f32) {
    return f32 ? ((const float*)p)[i] : bf2f(((const u16*)p)[i]);
}

// ---------------- kernel 1: h1 = relu(bld @ W1 + b1) -> bf16 stash in out[0..65536) --------
__global__ void h1_kernel(const void* __restrict__ bld, const void* __restrict__ W1,
                          const void* __restrict__ b1, u16* __restrict__ h1) {
    const bool bldf = sniff_f32(bld);
    const bool w1f  = sniff_f32(W1);
    const bool b1f  = sniff_f32(b1);
    const int b = blockIdx.x;
    const int j = threadIdx.x;
    float acc = ldr(b1, j, b1f);
#pragma unroll
    for (int k = 0; k < 8; k++)
        acc += ldr(bld, b * 8 + k, bldf) * ldr(W1, k * HYP + j, w1f);
    h1[b * HYP + j] = f2bf(fmaxf(acc, 0.f));
}

// ---------------- kernel 2: flat = h1 @ W2 + b2 (PERSISTENT grid, ring-4 B prefetch) -------
// Grid = 256 blocks (1/CU, zero block turnover). Each block loops its column-chunks.
// B prefetch ring of 4 register slots = 3 iterations in flight (~930+ cyc >= HBM latency).
// Double-buffered LDS tile, ONE raw barrier per K-step. A-fragments prefetched 1 step
// ahead (A is L2/L3-resident: 256 KB shared by all blocks).
constexpr int KS_ = 32;              // k per stage step
constexpr int NST = HYP / KS_;       // 16
constexpr int TKP = 40;              // padded k-dim in u16 (32 + 8) -> 80B rows
constexpr int NCH = (GN + 63) / 64;  // 1141 column chunks

template<bool W2F32>
__device__ void gemm_body(const u16* __restrict__ A, const void* __restrict__ Bm,
                          const void* __restrict__ b2, bool b2f,
                          float* __restrict__ out) {
    __shared__ alignas(16) u16 tileT[2][64][TKP];   // 10240 B

    const int tid  = threadIdx.x;
    const int lane = tid & 63;
    const int wid  = tid >> 6;
    const int l15  = lane & 15;
    const int q    = lane >> 4;

    const u16* ap[4];
#pragma unroll
    for (int i = 0; i < 4; i++)
        ap[i] = A + (wid * 64 + i * 16 + l15) * HYP + q * 8;

    const int scol_i = tid & 63;
    const int kq     = tid >> 6;          // 0..3

    for (int c = blockIdx.x; c < NCH; c += 256) {
        const int nb = c * 64;

        int  col[4]; bool cv[4];
#pragma unroll
        for (int j = 0; j < 4; j++) {
            int cc = nb + j * 16 + l15;
            cv[j]  = (cc < GN);
            col[j] = cv[j] ? cc : (GN - 1);
        }
        int gc = nb + scol_i;
        if (gc >= GN) gc = GN - 1;            // tail clamp (values masked at store)
        const size_t colOff = (size_t)gc;

        float pf[4][8]; u16 pb[4][8];         // B ring: slot s holds a 8-k column strip
        short8 afc[4];                        // A fragments for the CURRENT step

        // ---- prologue: stage B(0) direct; load B(1..3) into ring slots 1..3; A(0) --------
        {
            float t0[8]; u16 t1[8];
#pragma unroll
            for (int e = 0; e < 8; e++) {
                const size_t ro = (size_t)(kq * 8 + e) * (size_t)GN + colOff;
                if constexpr (W2F32) t0[e] = ((const float*)Bm)[ro];
                else                 t1[e] = ((const u16*)Bm)[ro];
            }
            short8 wv8;
#pragma unroll
            for (int e = 0; e < 8; e++) {
                if constexpr (W2F32) wv8[e] = (short)f2bf(t0[e]);
                else                 wv8[e] = (short)t1[e];
            }
            *(short8*)&tileT[0][scol_i][kq * 8] = wv8;
        }
#pragma unroll
        for (int s = 1; s < 4; s++) {
#pragma unroll
            for (int e = 0; e < 8; e++) {
                const size_t ro = (size_t)(s * KS_ + kq * 8 + e) * (size_t)GN + colOff;
                if constexpr (W2F32) pf[s][e] = ((const float*)Bm)[ro];
                else                 pb[s][e] = ((const u16*)Bm)[ro];
            }
        }
#pragma unroll
        for (int i = 0; i < 4; i++) afc[i] = *(const short8*)(ap[i]);
        bar_lds();

        floatx4 acc[4][4] = {};

#pragma unroll
        for (int ks = 0; ks < NST; ks++) {
            const int cur = ks & 1;

            short8 bfr[4];
#pragma unroll
            for (int j = 0; j < 4; j++)
                bfr[j] = *(const short8*)&tileT[cur][j * 16 + l15][q * 8];

            short8 afn[4];
            if (ks + 1 < NST) {
#pragma unroll
                for (int i = 0; i < 4; i++)
                    afn[i] = *(const short8*)(ap[i] + (ks + 1) * KS_);
            }
            if (ks + 4 < NST) {   // issue tile ks+4 into ring slot ks%4 (3 iters in flight)
#pragma unroll
                for (int e = 0; e < 8; e++) {
                    const size_t ro = (size_t)((ks + 4) * KS_ + kq * 8 + e) * (size_t)GN + colOff;
                    if constexpr (W2F32) pf[ks % 4][e] = ((const float*)Bm)[ro];
                    else                 pb[ks % 4][e] = ((const u16*)Bm)[ro];
                }
            }
            if (ks + 1 < NST) {   // write tile ks+1 (ring slot (ks+1)%4) into other buffer
                short8 wv8;
#pragma unroll
                for (int e = 0; e < 8; e++) {
                    if constexpr (W2F32) wv8[e] = (short)f2bf(pf[(ks + 1) % 4][e]);
                    else                 wv8[e] = (short)pb[(ks + 1) % 4][e];
                }
                *(short8*)&tileT[cur ^ 1][scol_i][kq * 8] = wv8;
            }

#pragma unroll
            for (int i = 0; i < 4; i++)
#pragma unroll
                for (int j = 0; j < 4; j++)
                    acc[i][j] = __builtin_amdgcn_mfma_f32_16x16x32_bf16(afc[i], bfr[j], acc[i][j], 0, 0, 0);
            bar_lds();   // writes of tile ks+1 visible; reads of tile ks drained

#pragma unroll
            for (int i = 0; i < 4; i++) afc[i] = afn[i];
        }

        const bool isP2 = (nb >= N1_);   // N1_ multiple of 64 -> no straddle
#pragma unroll
        for (int j = 0; j < 4; j++) {
            const float bias = ldr(b2, col[j], b2f);
#pragma unroll
            for (int i = 0; i < 4; i++) {
                const int mbase = wid * 64 + i * 16 + q * 4;
#pragma unroll
                for (int r = 0; r < 4; r++) {
                    if (cv[j]) {
                        const float v = acc[i][j][r] + bias;
                        const int m = mbase + r;
                        size_t dst;
                        if (isP2) dst = OUT_P2 + (size_t)m * N2_ + (size_t)(col[j] - N1_);
                        else      dst = OUT_P1 + (size_t)m * N1_ + (size_t)col[j];
                        out[dst] = v;
                    }
                }
            }
        }
    }
}
__global__ __launch_bounds__(256) void gemm_kernel(const u16* A, const void* Bm,
                                                   const void* b2, float* out) {
    const bool w2f = sniff_f32(Bm);
    const bool b2f = sniff_f32(b2);
    if (w2f) gemm_body<true>(A, Bm, b2, b2f, out);
    else     gemm_body<false>(A, Bm, b2, b2f, out);
}

// ---------------- kernel 3: per-batch RNN scan via MFMA, 8 waves (FROZEN from r6) ---------
// x_proj precomputed via one-time MFMA pass into hist[t+1] slots; scan reads the xp
// scalar and overwrites it in place with h_{t+1}. Per step/wave: 8 ds_read_b128 +
// 16 MFMA (setprio-wrapped) + 1 u16 read + tanh + 1 b16 write + ONE raw barrier.
constexpr int HROW = 256;            // hist row in halfs (512 B)
constexpr int XROW = 40;             // stim row in halfs (80 B, 16B-aligned)

__global__ __launch_bounds__(512, 1) void rnn_kernel(const void* __restrict__ stim,
                                                     float* __restrict__ out) {
    const bool stf = sniff_f32(stim);
    const int b    = blockIdx.x;
    const int tid  = threadIdx.x;
    const int lane = tid & 63;
    const int wv   = tid >> 6;       // 0..7
    const int l15  = lane & 15;
    const int q    = lane >> 4;      // 0..3

    const float* p1 = out + OUT_P1 + (size_t)b * N1_;
    const float* p2 = out + OUT_P2 + (size_t)b * N2_;

    __shared__ alignas(16) half_t hist[(T_ + 1) * HROW];   // 131584 B
    __shared__ alignas(16) half_t stim_s[T_ * XROW];       // 20480 B

    // ---- stage stimulus: row t holds x_ext = [x_{t-1}(16), 1.0, 0 x23]; row0 x = 0 -------
    if (stf) {
        const float2* sp = (const float2*)stim + (size_t)b * T_ * 8;
        for (int idx = tid; idx < (T_ - 1) * 8; idx += 512) {
            const int tt = idx >> 3, pr = idx & 7;
            float2 v = sp[idx];
            half2_t h; h.x = (half_t)v.x; h.y = (half_t)v.y;
            *(half2_t*)&stim_s[(tt + 1) * XROW + pr * 2] = h;
        }
    } else {
        const u32* sp = (const u32*)((const u16*)stim + (size_t)b * T_ * I_);
        for (int idx = tid; idx < (T_ - 1) * 8; idx += 512) {
            const int tt = idx >> 3, pr = idx & 7;
            u32 u = sp[idx];
            union { u32 i; float f; } lo2, hi2;
            lo2.i = u << 16; hi2.i = u & 0xffff0000u;
            half2_t h; h.x = (half_t)lo2.f; h.y = (half_t)hi2.f;
            *(half2_t*)&stim_s[(tt + 1) * XROW + pr * 2] = h;
        }
    }
    {   // per-row constants: halfs[16]=1.0, halfs[17..39]=0; row0 x zeros; hist row0 zeros
        u32* ss = (u32*)stim_s;
        if (tid < 256) {
            const int base = tid * (XROW / 2);   // this thread owns row `tid`
            ss[base + 8] = 0x00003C00u;          // halfs 16,17 = {1.0h, 0}
#pragma unroll
            for (int z = 9; z < XROW / 2; z++) ss[base + z] = 0u;
        }
        if (tid < 8)   ss[tid] = 0u;                  // row0 halfs 0..15
        if (tid < 128) ((u32*)hist)[tid] = 0u;        // h0 = 0
    }

    // ---- W fragments (B-side): lane holds W[g = 32*wv + it*16 + l15][kt*32 + q*8 + j] ----
    halfx8 Wf[2][8];   // W_hh only (scan)
    halfx8 Wx[2];      // x-tile: W_ih row | combined bias (precompute only)
    {
        const float* WH  = p1 + H_ * I_;               // W_hh [256][256]
        const float* BIH = p1 + H_ * I_ + H_ * H_;     // b_ih (then b_hh at +H_)
#pragma unroll
        for (int it = 0; it < 2; it++) {
            const int rr = 32 * wv + it * 16 + l15;
#pragma unroll
            for (int kt = 0; kt < 8; kt++) {
                const float4* wp = (const float4*)(WH + (size_t)rr * H_ + kt * 32 + q * 8);
                float4 r0 = wp[0], r1 = wp[1];
                halfx8 f;
                f[0] = (half_t)r0.x; f[1] = (half_t)r0.y; f[2] = (half_t)r0.z; f[3] = (half_t)r0.w;
                f[4] = (half_t)r1.x; f[5] = (half_t)r1.y; f[6] = (half_t)r1.z; f[7] = (half_t)r1.w;
                Wf[it][kt] = f;
            }
            // x-tile: k<16 -> W_ih row, k==16 -> combined bias, else 0
            halfx8 fx;
#pragma unroll
            for (int j = 0; j < 8; j++) fx[j] = (half_t)0.f;
            if (q < 2) {
                const float4* ip = (const float4*)(p1 + (size_t)rr * I_ + q * 8);
                float4 r0 = ip[0], r1 = ip[1];
                fx[0] = (half_t)r0.x; fx[1] = (half_t)r0.y; fx[2] = (half_t)r0.z; fx[3] = (half_t)r0.w;
                fx[4] = (half_t)r1.x; fx[5] = (half_t)r1.y; fx[6] = (half_t)r1.z; fx[7] = (half_t)r1.w;
            } else if (q == 2) {
                fx[0] = (half_t)(BIH[rr] + BIH[H_ + rr]);
            }
            Wx[it] = fx;
        }
    }
    __syncthreads();   // stim_s + hist row0 visible

    // ---- precompute x_proj[t] -> hist[t+1] (one-time MFMA pass over all t) ---------------
#pragma unroll
    for (int tm = 0; tm < 16; tm++) {
        halfx8 ax = *(const halfx8*)(stim_s + (size_t)(16 * tm + l15) * XROW + q * 8);
        floatx4 xa0 = __builtin_amdgcn_mfma_f32_16x16x32_f16(ax, Wx[0], floatx4{}, 0, 0, 0);
        floatx4 xa1 = __builtin_amdgcn_mfma_f32_16x16x32_f16(ax, Wx[1], floatx4{}, 0, 0, 0);
#pragma unroll
        for (int r = 0; r < 4; r++) {
            const int trow = 16 * tm + 4 * q + r;
            hist[(size_t)(trow + 1) * HROW + 32 * wv + l15]      = (half_t)xa0[r];
            hist[(size_t)(trow + 1) * HROW + 32 * wv + 16 + l15] = (half_t)xa1[r];
        }
    }
    __syncthreads();   // xp slots visible to all waves

    // ---- scan ----------------------------------------------------------------------------
    const int g32 = 32 * wv + (lane & 31);
    for (int t = 0; t < T_; t++) {
        halfx8 af[8];
        const half_t* hr = hist + (size_t)t * HROW + q * 8;
#pragma unroll
        for (int kt = 0; kt < 8; kt++)
            af[kt] = *(const halfx8*)(hr + kt * 32);
        const float xp = (float)hist[(size_t)(t + 1) * HROW + g32];   // xp slot (pre-h)

        floatx4 acc0 = {}, acc1 = {};
        __builtin_amdgcn_s_setprio(1);
#pragma unroll
        for (int kt = 0; kt < 8; kt++) {
            acc0 = __builtin_amdgcn_mfma_f32_16x16x32_f16(af[kt], Wf[0][kt], acc0, 0, 0, 0);
            acc1 = __builtin_amdgcn_mfma_f32_16x16x32_f16(af[kt], Wf[1][kt], acc1, 0, 0, 0);
        }
        __builtin_amdgcn_s_setprio(0);

        if (lane < 32) {
            const float s  = ((lane < 16) ? acc0[0] : acc1[0]) + xp;   // col = lane&15
            const float e  = __expf(2.f * s);
            const float hn = 1.f - 2.f / (e + 1.f);   // tanh(s)
            hist[(size_t)(t + 1) * HROW + g32] = (half_t)hn;           // overwrite xp slot
            if (t == T_ - 1) out[OUT_H + (size_t)b * H_ + g32] = hn;
        }
        bar_lds();   // ONE barrier/step (covers h-writes; no vmcnt drain)
    }

    // ---- post-pass: out2 = hist(T x 256) @ W_out^T via MFMA ------------------------------
    halfx8 Wo[8];
    float bo = 0.f;
    {
#pragma unroll
        for (int kt = 0; kt < 8; kt++) {
            halfx8 f;
#pragma unroll
            for (int j = 0; j < 8; j++) f[j] = (half_t)0.f;
            if (l15 < O_) {
                const float* wp = p2 + (size_t)l15 * H_ + kt * 32 + q * 8;   // 4B-aligned only
#pragma unroll
                for (int j = 0; j < 8; j++) f[j] = (half_t)wp[j];
            }
            Wo[kt] = f;
        }
        if (l15 < O_) bo = p2[O_ * H_ + l15];
    }

#pragma unroll
    for (int m = 0; m < 2; m++) {
        const int tb = (2 * wv + m) * 16;     // t' base for this M-tile
        const half_t* hr = hist + (size_t)(tb + l15 + 1) * HROW + q * 8;
        floatx4 acc = {};
#pragma unroll
        for (int kt = 0; kt < 8; kt++) {
            halfx8 a = *(const halfx8*)(hr + kt * 32);
            acc = __builtin_amdgcn_mfma_f32_16x16x32_f16(a, Wo[kt], acc, 0, 0, 0);
        }
        if (l15 < O_) {
            const int o = l15;
#pragma unroll
            for (int r = 0; r < 4; r++) {
                const int tt = tb + q * 4 + r;
                float v2 = acc[r] + bo;
                if (o < 3) out[OUT_ACT + (size_t)b * T_ * 3 + (size_t)tt * 3 + o] = 1.f / (1.f + __expf(-v2));
                else       out[OUT_BLDI + (size_t)b * T_ * 8 + (size_t)tt * 8 + (o - 3)] = v2;
            }
        }
    }
}

extern "C" void kernel_launch(void* const* d_in, const int* in_sizes, int n_in,
                              void* d_out, int out_size, void* d_ws, size_t ws_size,
                              hipStream_t stream) {
    (void)in_sizes; (void)n_in; (void)out_size; (void)d_ws; (void)ws_size;
    const void* bld  = d_in[0];
    const void* stim = d_in[1];
    const void* W1   = d_in[2];
    const void* b1   = d_in[3];
    const void* W2   = d_in[4];
    const void* b2   = d_in[5];
    float* out = (float*)d_out;
    u16* h1 = (u16*)out;   // 256x512 bf16 stash inside act region (rewritten by rnn post-pass)

    h1_kernel<<<B_, HYP, 0, stream>>>(bld, W1, b1, h1);
    gemm_kernel<<<256, 256, 0, stream>>>(h1, W2, b2, out);
    rnn_kernel<<<B_, 512, 0, stream>>>(stim, out);
}

// Round 10
// 411.012 us; speedup vs baseline: 1.4710x; 1.0078x over previous
//
#include <hip/hip_runtime.h>

typedef unsigned short u16;
typedef unsigned int u32;
using short4_t = __attribute__((ext_vector_type(4))) short;
using short8   = __attribute__((ext_vector_type(8))) short;
using floatx4  = __attribute__((ext_vector_type(4))) float;
using half_t   = _Float16;
using half2_t  = __attribute__((ext_vector_type(2))) _Float16;
using halfx8   = __attribute__((ext_vector_type(8))) _Float16;

constexpr int B_ = 256, T_ = 256, I_ = 16, H_ = 256, O_ = 11;
constexpr int HYP = 512;
constexpr int N1_ = H_ * I_ + H_ * H_ + 2 * H_;   // 70144
constexpr int N2_ = O_ * H_ + O_;                 // 2827
constexpr int GN  = N1_ + N2_;                    // 72971

// d_out is float32; offsets in float elements
constexpr size_t OUT_ACT  = 0;
constexpr size_t OUT_BLDI = (size_t)B_ * T_ * 3;            // 196608
constexpr size_t OUT_H    = OUT_BLDI + (size_t)B_ * T_ * 8; // 720896
constexpr size_t OUT_P1   = OUT_H + (size_t)B_ * H_;        // 786432
constexpr size_t OUT_P2   = OUT_P1 + (size_t)B_ * N1_;      // 18743296

// Raw workgroup barrier: LDS ordering only (no vmcnt drain).
__device__ inline void bar_lds() {
    asm volatile("s_waitcnt lgkmcnt(0)\n\ts_barrier" ::: "memory");
}

__device__ inline float bf2f(u16 u) {
    union { u32 i; float f; } v; v.i = ((u32)u) << 16; return v.f;
}
__device__ inline u16 f2bf(float f) {
    u32 x = __float_as_uint(f);
    u32 r = (x + 0x7fffu + ((x >> 16) & 1u)) >> 16;   // RNE, finite inputs
    return (u16)r;
}

// Per-tensor dtype sniff (wave-uniform).
__device__ inline bool sniff_f32(const void* p) {
    const u16* w = (const u16*)p;
    const int lane = threadIdx.x & 63;
    u16 u = w[lane * 2];
    unsigned e = (u >> 7) & 0xFF;
    bool inband = (u == 0) || (e >= 77 && e <= 140);
    return __popcll(__ballot(inband)) < 56;
}

__device__ inline float ldr(const void* p, size_t i, bool f32) {
    return f32 ? ((const float*)p)[i] : bf2f(((const u16*)p)[i]);
}

// ---------------- kernel 1: h1 = relu(bld @ W1 + b1) -> bf16 stash in out[0..65536) --------
__global__ void h1_kernel(const void* __restrict__ bld, const void* __restrict__ W1,
                          const void* __restrict__ b1, u16* __restrict__ h1) {
    const bool bldf = sniff_f32(bld);
    const bool w1f  = sniff_f32(W1);
    const bool b1f  = sniff_f32(b1);
    const int b = blockIdx.x;
    const int j = threadIdx.x;
    float acc = ldr(b1, j, b1f);
#pragma unroll
    for (int k = 0; k < 8; k++)
        acc += ldr(bld, b * 8 + k, bldf) * ldr(W1, k * HYP + j, w1f);
    h1[b * HYP + j] = f2bf(fmaxf(acc, 0.f));
}

// ---------------- kernel 2: flat = h1 @ W2 + b2 (PERSISTENT, 8 waves = 2/SIMD) -------------
// v9: 512 thr. Each wave owns 32 A-rows (acc[2][4], 8 MFMA/step); 2 waves/SIMD so the
// sibling wave's MFMA issue hides ds_read latency + barrier jitter (the r4->r5 rnn fix,
// transplanted). Staging: thread owns (col = tid&63, k-quad = tid>>6), 4 dwords/step.
// Ring-4 B prefetch (lookahead ~1240 cyc > 900 cyc HBM). ONE raw barrier per K-step.
constexpr int KS_ = 32;              // k per stage step
constexpr int NST = HYP / KS_;       // 16
constexpr int TKP = 40;              // padded k-dim in u16 (32 + 8) -> 80B rows
constexpr int NCH = (GN + 63) / 64;  // 1141 column chunks

template<bool W2F32>
__device__ void gemm_body(const u16* __restrict__ A, const void* __restrict__ Bm,
                          const void* __restrict__ b2, bool b2f,
                          float* __restrict__ out) {
    __shared__ alignas(16) u16 tileT[2][64][TKP];   // 10240 B

    const int tid  = threadIdx.x;
    const int lane = tid & 63;
    const int wid  = tid >> 6;            // 0..7
    const int l15  = lane & 15;
    const int q    = lane >> 4;

    const u16* ap[2];
#pragma unroll
    for (int i = 0; i < 2; i++)
        ap[i] = A + (wid * 32 + i * 16 + l15) * HYP + q * 8;

    const int scol_i = tid & 63;
    const int kq     = tid >> 6;          // 0..7 (4 k's each)

    for (int c = blockIdx.x; c < NCH; c += 256) {
        const int nb = c * 64;

        int  col[4]; bool cv[4];
#pragma unroll
        for (int j = 0; j < 4; j++) {
            int cc = nb + j * 16 + l15;
            cv[j]  = (cc < GN);
            col[j] = cv[j] ? cc : (GN - 1);
        }
        int gc = nb + scol_i;
        if (gc >= GN) gc = GN - 1;            // tail clamp (values masked at store)
        const size_t colOff = (size_t)gc;

        float pf[4][4]; u16 pb[4][4];         // B ring: slot s holds 4 k-rows of this col
        short8 afc[2];                        // A fragments for the CURRENT step

        // ---- prologue: stage B(0) direct; load B(1..3) into ring slots 1..3; A(0) --------
        {
            float t0[4]; u16 t1[4];
#pragma unroll
            for (int e = 0; e < 4; e++) {
                const size_t ro = (size_t)(kq * 4 + e) * (size_t)GN + colOff;
                if constexpr (W2F32) t0[e] = ((const float*)Bm)[ro];
                else                 t1[e] = ((const u16*)Bm)[ro];
            }
            short4_t wv4;
#pragma unroll
            for (int e = 0; e < 4; e++) {
                if constexpr (W2F32) wv4[e] = (short)f2bf(t0[e]);
                else                 wv4[e] = (short)t1[e];
            }
            *(short4_t*)&tileT[0][scol_i][kq * 4] = wv4;   // 8B-aligned
        }
#pragma unroll
        for (int s = 1; s < 4; s++) {
#pragma unroll
            for (int e = 0; e < 4; e++) {
                const size_t ro = (size_t)(s * KS_ + kq * 4 + e) * (size_t)GN + colOff;
                if constexpr (W2F32) pf[s][e] = ((const float*)Bm)[ro];
                else                 pb[s][e] = ((const u16*)Bm)[ro];
            }
        }
#pragma unroll
        for (int i = 0; i < 2; i++) afc[i] = *(const short8*)(ap[i]);
        bar_lds();

        floatx4 acc[2][4] = {};

#pragma unroll
        for (int ks = 0; ks < NST; ks++) {
            const int cur = ks & 1;

            short8 bfr[4];
#pragma unroll
            for (int j = 0; j < 4; j++)
                bfr[j] = *(const short8*)&tileT[cur][j * 16 + l15][q * 8];

            short8 afn[2];
            if (ks + 1 < NST) {
#pragma unroll
                for (int i = 0; i < 2; i++)
                    afn[i] = *(const short8*)(ap[i] + (ks + 1) * KS_);
            }
            if (ks + 4 < NST) {   // issue tile ks+4 into ring slot ks%4 (3 iters in flight)
#pragma unroll
                for (int e = 0; e < 4; e++) {
                    const size_t ro = (size_t)((ks + 4) * KS_ + kq * 4 + e) * (size_t)GN + colOff;
                    if constexpr (W2F32) pf[ks % 4][e] = ((const float*)Bm)[ro];
                    else                 pb[ks % 4][e] = ((const u16*)Bm)[ro];
                }
            }
            if (ks + 1 < NST) {   // write tile ks+1 (ring slot (ks+1)%4) into other buffer
                short4_t wv4;
#pragma unroll
                for (int e = 0; e < 4; e++) {
                    if constexpr (W2F32) wv4[e] = (short)f2bf(pf[(ks + 1) % 4][e]);
                    else                 wv4[e] = (short)pb[(ks + 1) % 4][e];
                }
                *(short4_t*)&tileT[cur ^ 1][scol_i][kq * 4] = wv4;
            }

#pragma unroll
            for (int i = 0; i < 2; i++)
#pragma unroll
                for (int j = 0; j < 4; j++)
                    acc[i][j] = __builtin_amdgcn_mfma_f32_16x16x32_bf16(afc[i], bfr[j], acc[i][j], 0, 0, 0);
            bar_lds();   // writes of tile ks+1 visible; reads of tile ks drained

#pragma unroll
            for (int i = 0; i < 2; i++) afc[i] = afn[i];
        }

        const bool isP2 = (nb >= N1_);   // N1_ multiple of 64 -> no straddle
#pragma unroll
        for (int j = 0; j < 4; j++) {
            const float bias = ldr(b2, col[j], b2f);
#pragma unroll
            for (int i = 0; i < 2; i++) {
                const int mbase = wid * 32 + i * 16 + q * 4;
#pragma unroll
                for (int r = 0; r < 4; r++) {
                    if (cv[j]) {
                        const float v = acc[i][j][r] + bias;
                        const int m = mbase + r;
                        size_t dst;
                        if (isP2) dst = OUT_P2 + (size_t)m * N2_ + (size_t)(col[j] - N1_);
                        else      dst = OUT_P1 + (size_t)m * N1_ + (size_t)col[j];
                        out[dst] = v;
                    }
                }
            }
        }
    }
}
__global__ __launch_bounds__(512) void gemm_kernel(const u16* A, const void* Bm,
                                                   const void* b2, float* out) {
    const bool w2f = sniff_f32(Bm);
    const bool b2f = sniff_f32(b2);
    if (w2f) gemm_body<true>(A, Bm, b2, b2f, out);
    else     gemm_body<false>(A, Bm, b2, b2f, out);
}

// ---------------- kernel 3: per-batch RNN scan via MFMA, 8 waves (FROZEN, r6/r7-stable) ---
// x_proj precomputed via one-time MFMA pass into hist[t+1] slots; scan reads the xp
// scalar and overwrites it in place with h_{t+1}. Per step/wave: 8 ds_read_b128 +
// 16 MFMA (setprio-wrapped) + 1 u16 read + tanh + 1 b16 write + ONE raw barrier.
constexpr int HROW = 256;            // hist row in halfs (512 B)
constexpr int XROW = 40;             // stim row in halfs (80 B, 16B-aligned)

__global__ __launch_bounds__(512, 1) void rnn_kernel(const void* __restrict__ stim,
                                                     float* __restrict__ out) {
    const bool stf = sniff_f32(stim);
    const int b    = blockIdx.x;
    const int tid  = threadIdx.x;
    const int lane = tid & 63;
    const int wv   = tid >> 6;       // 0..7
    const int l15  = lane & 15;
    const int q    = lane >> 4;      // 0..3

    const float* p1 = out + OUT_P1 + (size_t)b * N1_;
    const float* p2 = out + OUT_P2 + (size_t)b * N2_;

    __shared__ alignas(16) half_t hist[(T_ + 1) * HROW];   // 131584 B
    __shared__ alignas(16) half_t stim_s[T_ * XROW];       // 20480 B

    // ---- stage stimulus: row t holds x_ext = [x_{t-1}(16), 1.0, 0 x23]; row0 x = 0 -------
    if (stf) {
        const float2* sp = (const float2*)stim + (size_t)b * T_ * 8;
        for (int idx = tid; idx < (T_ - 1) * 8; idx += 512) {
            const int tt = idx >> 3, pr = idx & 7;
            float2 v = sp[idx];
            half2_t h; h.x = (half_t)v.x; h.y = (half_t)v.y;
            *(half2_t*)&stim_s[(tt + 1) * XROW + pr * 2] = h;
        }
    } else {
        const u32* sp = (const u32*)((const u16*)stim + (size_t)b * T_ * I_);
        for (int idx = tid; idx < (T_ - 1) * 8; idx += 512) {
            const int tt = idx >> 3, pr = idx & 7;
            u32 u = sp[idx];
            union { u32 i; float f; } lo2, hi2;
            lo2.i = u << 16; hi2.i = u & 0xffff0000u;
            half2_t h; h.x = (half_t)lo2.f; h.y = (half_t)hi2.f;
            *(half2_t*)&stim_s[(tt + 1) * XROW + pr * 2] = h;
        }
    }
    {   // per-row constants: halfs[16]=1.0, halfs[17..39]=0; row0 x zeros; hist row0 zeros
        u32* ss = (u32*)stim_s;
        if (tid < 256) {
            const int base = tid * (XROW / 2);   // this thread owns row `tid`
            ss[base + 8] = 0x00003C00u;          // halfs 16,17 = {1.0h, 0}
#pragma unroll
            for (int z = 9; z < XROW / 2; z++) ss[base + z] = 0u;
        }
        if (tid < 8)   ss[tid] = 0u;                  // row0 halfs 0..15
        if (tid < 128) ((u32*)hist)[tid] = 0u;        // h0 = 0
    }

    // ---- W fragments (B-side): lane holds W[g = 32*wv + it*16 + l15][kt*32 + q*8 + j] ----
    halfx8 Wf[2][8];   // W_hh only (scan)
    halfx8 Wx[2];      // x-tile: W_ih row | combined bias (precompute only)
    {
        const float* WH  = p1 + H_ * I_;               // W_hh [256][256]
        const float* BIH = p1 + H_ * I_ + H_ * H_;     // b_ih (then b_hh at +H_)
#pragma unroll
        for (int it = 0; it < 2; it++) {
            const int rr = 32 * wv + it * 16 + l15;
#pragma unroll
            for (int kt = 0; kt < 8; kt++) {
                const float4* wp = (const float4*)(WH + (size_t)rr * H_ + kt * 32 + q * 8);
                float4 r0 = wp[0], r1 = wp[1];
                halfx8 f;
                f[0] = (half_t)r0.x; f[1] = (half_t)r0.y; f[2] = (half_t)r0.z; f[3] = (half_t)r0.w;
                f[4] = (half_t)r1.x; f[5] = (half_t)r1.y; f[6] = (half_t)r1.z; f[7] = (half_t)r1.w;
                Wf[it][kt] = f;
            }
            // x-tile: k<16 -> W_ih row, k==16 -> combined bias, else 0
            halfx8 fx;
#pragma unroll
            for (int j = 0; j < 8; j++) fx[j] = (half_t)0.f;
            if (q < 2) {
                const float4* ip = (const float4*)(p1 + (size_t)rr * I_ + q * 8);
                float4 r0 = ip[0], r1 = ip[1];
                fx[0] = (half_t)r0.x; fx[1] = (half_t)r0.y; fx[2] = (half_t)r0.z; fx[3] = (half_t)r0.w;
                fx[4] = (half_t)r1.x; fx[5] = (half_t)r1.y; fx[6] = (half_t)r1.z; fx[7] = (half_t)r1.w;
            } else if (q == 2) {
                fx[0] = (half_t)(BIH[rr] + BIH[H_ + rr]);
            }
            Wx[it] = fx;
        }
    }
    __syncthreads();   // stim_s + hist row0 visible

    // ---- precompute x_proj[t] -> hist[t+1] (one-time MFMA pass over all t) ---------------
#pragma unroll
    for (int tm = 0; tm < 16; tm++) {
        halfx8 ax = *(const halfx8*)(stim_s + (size_t)(16 * tm + l15) * XROW + q * 8);
        floatx4 xa0 = __builtin_amdgcn_mfma_f32_16x16x32_f16(ax, Wx[0], floatx4{}, 0, 0, 0);
        floatx4 xa1 = __builtin_amdgcn_mfma_f32_16x16x32_f16(ax, Wx[1], floatx4{}, 0, 0, 0);
#pragma unroll
        for (int r = 0; r < 4; r++) {
            const int trow = 16 * tm + 4 * q + r;
            hist[(size_t)(trow + 1) * HROW + 32 * wv + l15]      = (half_t)xa0[r];
            hist[(size_t)(trow + 1) * HROW + 32 * wv + 16 + l15] = (half_t)xa1[r];
        }
    }
    __syncthreads();   // xp slots visible to all waves

    // ---- scan ----------------------------------------------------------------------------
    const int g32 = 32 * wv + (lane & 31);
    for (int t = 0; t < T_; t++) {
        halfx8 af[8];
        const half_t* hr = hist + (size_t)t * HROW + q * 8;
#pragma unroll
        for (int kt = 0; kt < 8; kt++)
            af[kt] = *(const halfx8*)(hr + kt * 32);
        const float xp = (float)hist[(size_t)(t + 1) * HROW + g32];   // xp slot (pre-h)

        floatx4 acc0 = {}, acc1 = {};
        __builtin_amdgcn_s_setprio(1);
#pragma unroll
        for (int kt = 0; kt < 8; kt++) {
            acc0 = __builtin_amdgcn_mfma_f32_16x16x32_f16(af[kt], Wf[0][kt], acc0, 0, 0, 0);
            acc1 = __builtin_amdgcn_mfma_f32_16x16x32_f16(af[kt], Wf[1][kt], acc1, 0, 0, 0);
        }
        __builtin_amdgcn_s_setprio(0);

        if (lane < 32) {
            const float s  = ((lane < 16) ? acc0[0] : acc1[0]) + xp;   // col = lane&15
            const float e  = __expf(2.f * s);
            const float hn = 1.f - 2.f / (e + 1.f);   // tanh(s)
            hist[(size_t)(t + 1) * HROW + g32] = (half_t)hn;           // overwrite xp slot
            if (t == T_ - 1) out[OUT_H + (size_t)b * H_ + g32] = hn;
        }
        bar_lds();   // ONE barrier/step (covers h-writes; no vmcnt drain)
    }

    // ---- post-pass: out2 = hist(T x 256) @ W_out^T via MFMA ------------------------------
    halfx8 Wo[8];
    float bo = 0.f;
    {
#pragma unroll
        for (int kt = 0; kt < 8; kt++) {
            halfx8 f;
#pragma unroll
            for (int j = 0; j < 8; j++) f[j] = (half_t)0.f;
            if (l15 < O_) {
                const float* wp = p2 + (size_t)l15 * H_ + kt * 32 + q * 8;   // 4B-aligned only
#pragma unroll
                for (int j = 0; j < 8; j++) f[j] = (half_t)wp[j];
            }
            Wo[kt] = f;
        }
        if (l15 < O_) bo = p2[O_ * H_ + l15];
    }

#pragma unroll
    for (int m = 0; m < 2; m++) {
        const int tb = (2 * wv + m) * 16;     // t' base for this M-tile
        const half_t* hr = hist + (size_t)(tb + l15 + 1) * HROW + q * 8;
        floatx4 acc = {};
#pragma unroll
        for (int kt = 0; kt < 8; kt++) {
            halfx8 a = *(const halfx8*)(hr + kt * 32);
            acc = __builtin_amdgcn_mfma_f32_16x16x32_f16(a, Wo[kt], acc, 0, 0, 0);
        }
        if (l15 < O_) {
            const int o = l15;
#pragma unroll
            for (int r = 0; r < 4; r++) {
                const int tt = tb + q * 4 + r;
                float v2 = acc[r] + bo;
                if (o < 3) out[OUT_ACT + (size_t)b * T_ * 3 + (size_t)tt * 3 + o] = 1.f / (1.f + __expf(-v2));
                else       out[OUT_BLDI + (size_t)b * T_ * 8 + (size_t)tt * 8 + (o - 3)] = v2;
            }
        }
    }
}

extern "C" void kernel_launch(void* const* d_in, const int* in_sizes, int n_in,
                              void* d_out, int out_size, void* d_ws, size_t ws_size,
                              hipStream_t stream) {
    (void)in_sizes; (void)n_in; (void)out_size; (void)d_ws; (void)ws_size;
    const void* bld  = d_in[0];
    const void* stim = d_in[1];
    const void* W1   = d_in[2];
    const void* b1   = d_in[3];
    const void* W2   = d_in[4];
    const void* b2   = d_in[5];
    float* out = (float*)d_out;
    u16* h1 = (u16*)out;   // 256x512 bf16 stash inside act region (rewritten by rnn post-pass)

    h1_kernel<<<B_, HYP, 0, stream>>>(bld, W1, b1, h1);
    gemm_kernel<<<256, 512, 0, stream>>>(h1, W2, b2, out);
    rnn_kernel<<<B_, 512, 0, stream>>>(stim, out);
}